// Round 7
// baseline (975.610 us; speedup 1.0000x reference)
//
#include <hip/hip_runtime.h>
#include <stdint.h>

typedef __attribute__((ext_vector_type(8))) short bf16x8;
typedef __attribute__((ext_vector_type(4))) float f32x4;
typedef unsigned short u16;

#define GLD_LDS16(g, l) __builtin_amdgcn_global_load_lds( \
    (const __attribute__((address_space(1))) void*)(g),   \
    (__attribute__((address_space(3))) void*)(l), 16, 0, 0)

#define ACCUM(d, a_, b_) d = __builtin_amdgcn_mfma_f32_16x16x32_bf16(a_, b_, d, 0, 0, 0)

__device__ __forceinline__ u16 f2bf(float f) {
  union { float f; uint32_t u; } a; a.f = f;
  uint32_t u = a.u;
  return (u16)((u + 0x7fffu + ((u >> 16) & 1u)) >> 16);
}
__device__ __forceinline__ float bf2f(u16 h) {
  union { uint32_t u; float f; } a; a.u = ((uint32_t)h) << 16;
  return a.f;
}
__device__ __forceinline__ bf16x8 ldsv(const u16* p) {
  union { uint4 u; bf16x8 v; } x;
  x.u = *(const uint4*)p;   // guaranteed ds_read_b128
  return x.v;
}

// ---------------- fused weight fp32 -> bf16 (contiguous dst) ----------------
__global__ __launch_bounds__(256) void wconv4(const float* __restrict__ a,
    const float* __restrict__ b, const float* __restrict__ c,
    const float* __restrict__ d, u16* __restrict__ out) {
  int i = blockIdx.x * 256 + threadIdx.x;
  const float* src; int off;
  if (i < 786432)       { src = a; off = i; }
  else if (i < 1048576) { src = b; off = i - 786432; }
  else if (i < 3145728) { src = c; off = i - 1048576; }
  else                  { src = d; off = i - 3145728; }
  out[i] = f2bf(src[off]);
}

// ---------------- LayerNorm (optionally fused shift+window gather) ----------------
template<bool WINDOW>
__global__ __launch_bounds__(256) void ln_win(const float* __restrict__ x,
    const float* __restrict__ gw, const float* __restrict__ bw,
    u16* __restrict__ out) {
  int wid = threadIdx.x >> 6;
  int lane = threadIdx.x & 63;
  int m = (blockIdx.x << 2) + wid;
  const float* src;
  if (WINDOW) {
    int n = m & 63;
    int bwin = m >> 6;
    int b = bwin >> 8;
    int wi = bwin & 255;
    int h = (((wi >> 4) << 3) + (n >> 3) + 4) & 127;
    int w = (((wi & 15) << 3) + (n & 7) + 4) & 127;
    src = x + (((size_t)((b << 7) + h) << 7) + (size_t)w) * 512;
  } else {
    src = x + ((size_t)m << 9);
  }
  int ch = lane << 3;
  float4 v0 = *(const float4*)(src + ch);
  float4 v1 = *(const float4*)(src + ch + 4);
  float vv[8] = {v0.x, v0.y, v0.z, v0.w, v1.x, v1.y, v1.z, v1.w};
  float s = 0.f, s2 = 0.f;
#pragma unroll
  for (int j = 0; j < 8; j++) { s += vv[j]; s2 += vv[j] * vv[j]; }
#pragma unroll
  for (int off = 32; off; off >>= 1) {
    s += __shfl_xor(s, off);
    s2 += __shfl_xor(s2, off);
  }
  float mean = s * (1.f / 512.f);
  float var = s2 * (1.f / 512.f) - mean * mean;
  float rstd = rsqrtf(var + 1e-5f);
  union { uint4 u; u16 h[8]; } pk;
#pragma unroll
  for (int j = 0; j < 8; j++)
    pk.h[j] = f2bf((vv[j] - mean) * rstd * gw[ch + j] + bw[ch + j]);
  *(uint4*)(out + ((size_t)m << 9) + ch) = pk.u;
}

// ---------------- 256x256-tile 8-phase bf16 MFMA GEMM (B^T weights) ----------------
// De-pinned m201-faithful schedule: per phase {reads; stage; s_barrier; lgkmcnt(0);
// setprio(1); 16 MFMA; setprio(0); s_barrier}. NO sched_barriers except one per
// K-tile after the gate (vmcnt(4)+barrier publishing buffer s+1).
template<int EPI, int K>
__global__ __launch_bounds__(512, 1) void gemm8(
    const u16* __restrict__ A, const u16* __restrict__ Bw,
    const float* __restrict__ bias, void* __restrict__ outp,
    const float* __restrict__ resid, int NTN) {
  __shared__ __align__(16) u16 lds[2][4][8192];  // [buf][A0,A1,B0,B1][16KB]
  const int NT = K / 64;
  int bid = blockIdx.x;
  int nwg = gridDim.x;
  int wg = (bid & 7) * (nwg >> 3) + (bid >> 3);   // bijective XCD swizzle (nwg%8==0)
  int mt = wg / NTN, nt = wg - mt * NTN;
  int m0 = mt << 8;
  int n0 = (EPI == 3) ? (nt << 7) : (nt << 8);

  int tid = threadIdx.x;
  int wid = tid >> 6, lane = tid & 63;
  int wm = wid >> 2, wn = wid & 3;
  int l15 = lane & 15, lhi = lane >> 4;
  int swz = (lane & 7) << 4;

  int sr0 = tid >> 3;
  int xk = (((tid & 7) ^ ((tid >> 3) & 7)) << 3);  // pre-swizzled source k-offset

  // hoisted per-wave stage source pointers (slot order: A0,A1,B0,B1)
  const u16* gA0p = A + (size_t)(m0 + sr0) * K + xk;
  const u16* gA1p = gA0p + (size_t)128 * K;
  const u16* gB0p;
  const u16* gB1p;
  if (EPI == 3) {
    gB0p = Bw + (size_t)(n0 + sr0) * K + xk;
    gB1p = Bw + (size_t)(2048 + n0 + sr0) * K + xk;
  } else {
    gB0p = Bw + (size_t)(n0 + sr0) * K + xk;
    gB1p = gB0p + (size_t)128 * K;
  }

  auto stage = [&](const u16* gp, int slot, int t) {
    if (t >= NT) return;
    u16* ld = &lds[t & 1][slot][0] + (wid << 9);  // wave-uniform dest
    const u16* g0 = gp + t * 64;
    GLD_LDS16(g0, ld);
    GLD_LDS16(g0 + (size_t)64 * K, ld + 4096);
  };

  f32x4 acc[2][4][2][2] = {};   // [qm][i][qn][j]
  bf16x8 afr[4][2], b0r[2][2], b1r[2][2];

  int aoffE = (wm * 64 + l15) * 64;
  int boffE = (wn * 32 + l15) * 64;
  int k0e = ((lhi * 16) ^ swz) >> 1;
  int k1e = ((64 + lhi * 16) ^ swz) >> 1;

  // prologue: tile0 all slots, then tile1 A0,B1; gate drains tile0 (oldest 8)
  stage(gA0p, 0, 0); stage(gB0p, 2, 0); stage(gA1p, 1, 0); stage(gB1p, 3, 0);
  stage(gA0p, 0, 1); stage(gB1p, 3, 1);
  asm volatile("s_waitcnt vmcnt(4)" ::: "memory");
  __builtin_amdgcn_s_barrier();
  __builtin_amdgcn_sched_barrier(0);

  for (int s = 0; s < NT; ++s) {
    const u16* Ah0 = &lds[s & 1][0][0];
    const u16* Ah1 = &lds[s & 1][1][0];
    const u16* Bh0 = &lds[s & 1][2][0];
    const u16* Bh1 = &lds[s & 1][3][0];

    // ---- phase 0: quadrant (A0,B0); stage B0(s+1)
#pragma unroll
    for (int i = 0; i < 4; i++) {
      afr[i][0] = ldsv(&Ah0[aoffE + i * 1024 + k0e]);
      afr[i][1] = ldsv(&Ah0[aoffE + i * 1024 + k1e]);
    }
#pragma unroll
    for (int j = 0; j < 2; j++) {
      b0r[j][0] = ldsv(&Bh0[boffE + j * 1024 + k0e]);
      b0r[j][1] = ldsv(&Bh0[boffE + j * 1024 + k1e]);
    }
    stage(gB0p, 2, s + 1);
    __builtin_amdgcn_s_barrier();
    asm volatile("s_waitcnt lgkmcnt(0)" ::: "memory");
    __builtin_amdgcn_s_setprio(1);
#pragma unroll
    for (int i = 0; i < 4; i++)
#pragma unroll
      for (int j = 0; j < 2; j++) {
        ACCUM(acc[0][i][0][j], afr[i][0], b0r[j][0]);
        ACCUM(acc[0][i][0][j], afr[i][1], b0r[j][1]);
      }
    __builtin_amdgcn_s_setprio(0);
    __builtin_amdgcn_s_barrier();

    // ---- phase 1: quadrant (A0,B1); stage A1(s+1)
#pragma unroll
    for (int j = 0; j < 2; j++) {
      b1r[j][0] = ldsv(&Bh1[boffE + j * 1024 + k0e]);
      b1r[j][1] = ldsv(&Bh1[boffE + j * 1024 + k1e]);
    }
    stage(gA1p, 1, s + 1);
    __builtin_amdgcn_s_barrier();
    asm volatile("s_waitcnt lgkmcnt(0)" ::: "memory");
    __builtin_amdgcn_s_setprio(1);
#pragma unroll
    for (int i = 0; i < 4; i++)
#pragma unroll
      for (int j = 0; j < 2; j++) {
        ACCUM(acc[0][i][1][j], afr[i][0], b1r[j][0]);
        ACCUM(acc[0][i][1][j], afr[i][1], b1r[j][1]);
      }
    __builtin_amdgcn_s_setprio(0);
    __builtin_amdgcn_s_barrier();

    // ---- phase 2: quadrant (A1,B1); stage A0(s+2)
#pragma unroll
    for (int i = 0; i < 4; i++) {
      afr[i][0] = ldsv(&Ah1[aoffE + i * 1024 + k0e]);
      afr[i][1] = ldsv(&Ah1[aoffE + i * 1024 + k1e]);
    }
    stage(gA0p, 0, s + 2);
    __builtin_amdgcn_s_barrier();
    asm volatile("s_waitcnt lgkmcnt(0)" ::: "memory");
    __builtin_amdgcn_s_setprio(1);
#pragma unroll
    for (int i = 0; i < 4; i++)
#pragma unroll
      for (int j = 0; j < 2; j++) {
        ACCUM(acc[1][i][1][j], afr[i][0], b1r[j][0]);
        ACCUM(acc[1][i][1][j], afr[i][1], b1r[j][1]);
      }
    __builtin_amdgcn_s_setprio(0);
    __builtin_amdgcn_s_barrier();

    // ---- phase 3: quadrant (A1,B0) (regs reused); stage B1(s+2)
    stage(gB1p, 3, s + 2);
    __builtin_amdgcn_s_setprio(1);
#pragma unroll
    for (int i = 0; i < 4; i++)
#pragma unroll
      for (int j = 0; j < 2; j++) {
        ACCUM(acc[1][i][0][j], afr[i][0], b0r[j][0]);
        ACCUM(acc[1][i][0][j], afr[i][1], b0r[j][1]);
      }
    __builtin_amdgcn_s_setprio(0);
    // gate: oldest 8 outstanding = all of tile s+1
    if (s >= NT - 2) { asm volatile("s_waitcnt vmcnt(0)" ::: "memory"); }
    else             { asm volatile("s_waitcnt vmcnt(4)" ::: "memory"); }
    __builtin_amdgcn_s_barrier();
    __builtin_amdgcn_sched_barrier(0);
  }

  // ---------------- epilogue ----------------
#pragma unroll
  for (int qm = 0; qm < 2; qm++)
#pragma unroll
    for (int i = 0; i < 4; i++) {
      int row = m0 + qm * 128 + wm * 64 + i * 16 + lhi * 4;
      if (EPI == 0) {
        u16* out = (u16*)outp;
#pragma unroll
        for (int qn = 0; qn < 2; qn++)
#pragma unroll
          for (int j = 0; j < 2; j++) {
            int col = n0 + qn * 128 + wn * 32 + j * 16 + l15;
            float bv = bias[col];
#pragma unroll
            for (int rg = 0; rg < 4; rg++)
              out[(size_t)(row + rg) * 1536 + col] = f2bf(acc[qm][i][qn][j][rg] + bv);
          }
      } else if (EPI == 1) {
        float* out = (float*)outp;
#pragma unroll
        for (int rg = 0; rg < 4; rg++) {
          int m = row + rg;
          int b = m >> 14, wi2 = (m >> 6) & 255, n = m & 63;
          int h = (((wi2 >> 4) << 3) + (n >> 3) + 4) & 127;
          int w = (((wi2 & 15) << 3) + (n & 7) + 4) & 127;
          size_t pix = (((size_t)((b << 7) + h) << 7) + (size_t)w) << 9;
#pragma unroll
          for (int qn = 0; qn < 2; qn++)
#pragma unroll
            for (int j = 0; j < 2; j++) {
              int col = n0 + qn * 128 + wn * 32 + j * 16 + l15;
              out[pix + col] = resid[pix + col] + acc[qm][i][qn][j][rg] + bias[col];
            }
        }
      } else if (EPI == 2) {
        float* out = (float*)outp;
#pragma unroll
        for (int qn = 0; qn < 2; qn++)
#pragma unroll
          for (int j = 0; j < 2; j++) {
            int col = n0 + qn * 128 + wn * 32 + j * 16 + l15;
            float bv = bias[col];
#pragma unroll
            for (int rg = 0; rg < 4; rg++) {
              size_t idx = (size_t)(row + rg) * 512 + col;
              out[idx] = out[idx] + acc[qm][i][qn][j][rg] + bv;
            }
          }
      } else {
        u16* out = (u16*)outp;
#pragma unroll
        for (int j = 0; j < 2; j++) {
          int col = n0 + wn * 32 + j * 16 + l15;
          float ba_ = bias[col], bg_ = bias[col + 2048];
#pragma unroll
          for (int rg = 0; rg < 4; rg++) {
            float av = acc[qm][i][0][j][rg] + ba_;
            float gv = acc[qm][i][1][j][rg] + bg_;
            float sw = gv / (1.f + __expf(-gv));
            out[(size_t)(row + rg) * 2048 + col] = f2bf(sw * av);
          }
        }
      }
    }
}

// ---------------- MFMA windowed attention: 1 wave per (window, head) -------------
__global__ __launch_bounds__(256) void attn_mfma(
    const u16* __restrict__ qkv, u16* __restrict__ out) {
  __shared__ __align__(16) char alds[4][15360];
  int tid = threadIdx.x;
  int wid = tid >> 6, lane = tid & 63;
  int bwin = blockIdx.x >> 2;
  int head = ((blockIdx.x & 3) << 2) + wid;
  int wi = bwin & 255;
  int wr = wi >> 4, wc = wi & 15;
  char* Wb = alds[wid];
  u16* Qr = (u16*)Wb;                 // [64] rows, 40 u16 stride (80B)
  u16* Kr = (u16*)(Wb + 5120);
  u16* Vt = (u16*)(Wb + 10240);       // [32][72 u16] (144B stride)
  u16* PT = (u16*)Wb;                 // [64][72 u16] — overlaps Qr/Kr after S
  int t = lane;
  int l15 = lane & 15, lhi = lane >> 4;
  const u16* base = qkv + (size_t)((bwin << 6) + t) * 1536 + (head << 5);
  union U { uint4 u; u16 s[8]; };
  U vq[4], vk[4], vv[4];
#pragma unroll
  for (int g = 0; g < 4; g++) {
    vq[g].u = *(const uint4*)(base + (g << 3));
    vk[g].u = *(const uint4*)(base + 512 + (g << 3));
    vv[g].u = *(const uint4*)(base + 1024 + (g << 3));
  }
  float q[32], k[32];
#pragma unroll
  for (int j = 0; j < 32; j++) {
    q[j] = bf2f(vq[j >> 3].s[j & 7]);
    k[j] = bf2f(vk[j >> 3].s[j & 7]);
  }
  int r = t >> 3, c = t & 7;
#pragma unroll
  for (int d = 0; d < 16; d++) {
    float pos = (d < 8) ? (float)r : (float)c;
    int dd = (d < 8) ? d : d - 8;
    float ang = pos * __expf(-(float)dd * 1.1512925465f);  // 10000^(-dd/8)
    float sn, cs;
    __sincosf(ang, &sn, &cs);
    float q1 = q[d], q2 = q[d + 16];
    q[d] = q1 * cs - q2 * sn;  q[d + 16] = q2 * cs + q1 * sn;
    float k1 = k[d], k2 = k[d + 16];
    k[d] = k1 * cs - k2 * sn;  k[d + 16] = k2 * cs + k1 * sn;
  }
#pragma unroll
  for (int j = 0; j < 32; j++) q[j] *= 0.17677669529663687f;  // 32^-0.5
#pragma unroll
  for (int sl = 0; sl < 4; sl++) {
    U tq, tk;
#pragma unroll
    for (int j = 0; j < 8; j++) { tq.s[j] = f2bf(q[sl * 8 + j]); tk.s[j] = f2bf(k[sl * 8 + j]); }
    *(uint4*)(Qr + t * 40 + sl * 8) = tq.u;
    *(uint4*)(Kr + t * 40 + sl * 8) = tk.u;
  }
#pragma unroll
  for (int j = 0; j < 32; j++) Vt[j * 72 + t] = vv[j >> 3].s[j & 7];
  // ---- S^T = K · Q^T
  bf16x8 kf[4], qf[4];
#pragma unroll
  for (int i = 0; i < 4; i++) {
    kf[i] = *(const bf16x8*)(Kr + (i * 16 + l15) * 40 + lhi * 8);
    qf[i] = *(const bf16x8*)(Qr + (i * 16 + l15) * 40 + lhi * 8);
  }
  f32x4 zz = {0.f, 0.f, 0.f, 0.f};
  f32x4 st[4][4];
#pragma unroll
  for (int mi = 0; mi < 4; mi++)
#pragma unroll
    for (int nj = 0; nj < 4; nj++)
      st[mi][nj] = __builtin_amdgcn_mfma_f32_16x16x32_bf16(kf[mi], qf[nj], zz, 0, 0, 0);
  if (wr == 15 || wc == 15) {
    int idh = (wr == 15) ? ((r >= 4) ? 2 : 1) : 0;
    int idw = (wc == 15) ? ((c >= 4) ? 2 : 1) : 0;
    int code = idh * 3 + idw;
    int cq[4], cm[4][4];
#pragma unroll
    for (int nj = 0; nj < 4; nj++) cq[nj] = __shfl(code, nj * 16 + l15);
#pragma unroll
    for (int mi = 0; mi < 4; mi++)
#pragma unroll
      for (int rg = 0; rg < 4; rg++) cm[mi][rg] = __shfl(code, mi * 16 + lhi * 4 + rg);
#pragma unroll
    for (int mi = 0; mi < 4; mi++)
#pragma unroll
      for (int nj = 0; nj < 4; nj++)
#pragma unroll
        for (int rg = 0; rg < 4; rg++)
          if (cm[mi][rg] != cq[nj]) st[mi][nj][rg] -= 100.f;
  }
  float inv_[4];
#pragma unroll
  for (int nj = 0; nj < 4; nj++) {
    float mx = -1e30f;
#pragma unroll
    for (int mi = 0; mi < 4; mi++)
#pragma unroll
      for (int rg = 0; rg < 4; rg++) mx = fmaxf(mx, st[mi][nj][rg]);
    mx = fmaxf(mx, __shfl_xor(mx, 16));
    mx = fmaxf(mx, __shfl_xor(mx, 32));
    float sum = 0.f;
#pragma unroll
    for (int mi = 0; mi < 4; mi++)
#pragma unroll
      for (int rg = 0; rg < 4; rg++) {
        float p = __expf(st[mi][nj][rg] - mx);
        st[mi][nj][rg] = p;
        sum += p;
      }
    sum += __shfl_xor(sum, 16);
    sum += __shfl_xor(sum, 32);
    inv_[nj] = 1.f / sum;
  }
#pragma unroll
  for (int mi = 0; mi < 4; mi++)
#pragma unroll
    for (int nj = 0; nj < 4; nj++) {
      uint32_t lo, hi;
      asm("v_cvt_pk_bf16_f32 %0, %1, %2" : "=v"(lo) : "v"(st[mi][nj][0]), "v"(st[mi][nj][1]));
      asm("v_cvt_pk_bf16_f32 %0, %1, %2" : "=v"(hi) : "v"(st[mi][nj][2]), "v"(st[mi][nj][3]));
      uint2 pr; pr.x = lo; pr.y = hi;
      *(uint2*)(PT + (nj * 16 + l15) * 72 + mi * 16 + lhi * 4) = pr;
    }
  bf16x8 vf[2][2], pf[4][2];
#pragma unroll
  for (int i = 0; i < 2; i++)
#pragma unroll
    for (int kc = 0; kc < 2; kc++)
      vf[i][kc] = *(const bf16x8*)(Vt + (i * 16 + l15) * 72 + kc * 32 + lhi * 8);
#pragma unroll
  for (int nj = 0; nj < 4; nj++)
#pragma unroll
    for (int kc = 0; kc < 2; kc++)
      pf[nj][kc] = *(const bf16x8*)(PT + (nj * 16 + l15) * 72 + kc * 32 + lhi * 8);
#pragma unroll
  for (int i = 0; i < 2; i++)
#pragma unroll
    for (int nj = 0; nj < 4; nj++) {
      f32x4 o = __builtin_amdgcn_mfma_f32_16x16x32_bf16(vf[i][0], pf[nj][0], zz, 0, 0, 0);
      o = __builtin_amdgcn_mfma_f32_16x16x32_bf16(vf[i][1], pf[nj][1], o, 0, 0, 0);
      float iv = inv_[nj];
      float o0 = o[0] * iv, o1 = o[1] * iv, o2 = o[2] * iv, o3 = o[3] * iv;
      uint32_t lo, hi;
      asm("v_cvt_pk_bf16_f32 %0, %1, %2" : "=v"(lo) : "v"(o0), "v"(o1));
      asm("v_cvt_pk_bf16_f32 %0, %1, %2" : "=v"(hi) : "v"(o2), "v"(o3));
      uint2 pr; pr.x = lo; pr.y = hi;
      *(uint2*)(out + (size_t)((bwin << 6) + nj * 16 + l15) * 512 + (head << 5) + i * 16 + lhi * 4) = pr;
    }
}

// ---------------- launch ----------------
extern "C" void kernel_launch(void* const* d_in, const int* in_sizes, int n_in,
                              void* d_out, int out_size, void* d_ws, size_t ws_size,
                              hipStream_t stream) {
  (void)in_sizes; (void)n_in; (void)out_size; (void)ws_size;
  const float* x      = (const float*)d_in[0];
  const float* n1g    = (const float*)d_in[2];
  const float* n1b    = (const float*)d_in[3];
  const float* qkv_w  = (const float*)d_in[4];
  const float* qkv_b  = (const float*)d_in[5];
  const float* proj_w = (const float*)d_in[6];
  const float* proj_b = (const float*)d_in[7];
  const float* n2g    = (const float*)d_in[8];
  const float* n2b    = (const float*)d_in[9];
  const float* fc1_w  = (const float*)d_in[10];
  const float* fc1_b  = (const float*)d_in[11];
  const float* fc2_w  = (const float*)d_in[12];
  const float* fc2_b  = (const float*)d_in[13];

  char* ws = (char*)d_ws;
  u16* wb_qkv  = (u16*)ws;                  // 1536*512
  u16* wb_proj = wb_qkv + 786432;           // 512*512
  u16* wb_fc1  = wb_proj + 262144;          // 4096*512
  u16* wb_fc2  = wb_fc1 + 2097152;          // 512*2048
  u16* xw      = (u16*)(ws + 8388608);      // xw, later attnout
  u16* qkvb    = (u16*)(ws + 8388608 + 67108864);   // qkv, later y
  u16* yb      = qkvb;
  u16* hb      = (u16*)(ws + 8388608 + 134217728);  // h
  u16* attnout = xw;

  wconv4<<<16384, 256, 0, stream>>>(qkv_w, proj_w, fc1_w, fc2_w, wb_qkv);
  ln_win<true><<<16384, 256, 0, stream>>>(x, n1g, n1b, xw);
  gemm8<0, 512><<<1536, 512, 0, stream>>>(xw, wb_qkv, qkv_b, qkvb, nullptr, 6);
  attn_mfma<<<4096, 256, 0, stream>>>(qkvb, attnout);
  gemm8<1, 512><<<512, 512, 0, stream>>>(attnout, wb_proj, proj_b, d_out, x, 2);
  ln_win<false><<<16384, 256, 0, stream>>>((const float*)d_out, n2g, n2b, yb);
  gemm8<3, 512><<<4096, 512, 0, stream>>>(yb, wb_fc1, fc1_b, hb, nullptr, 16);
  gemm8<2, 2048><<<512, 512, 0, stream>>>(hb, wb_fc2, fc2_b, d_out, nullptr, 2);
}

// Round 8
// 887.299 us; speedup vs baseline: 1.0995x; 1.0995x over previous
//
#include <hip/hip_runtime.h>
#include <stdint.h>

typedef __attribute__((ext_vector_type(8))) short bf16x8;
typedef __attribute__((ext_vector_type(4))) float f32x4;
typedef unsigned short u16;

#define GLD_LDS16(g, l) __builtin_amdgcn_global_load_lds( \
    (const __attribute__((address_space(1))) void*)(g),   \
    (__attribute__((address_space(3))) void*)(l), 16, 0, 0)

#define PB() do { __builtin_amdgcn_sched_barrier(0); \
                  __builtin_amdgcn_s_barrier();      \
                  __builtin_amdgcn_sched_barrier(0); } while (0)

#define ACCUM(d, a_, b_) d = __builtin_amdgcn_mfma_f32_16x16x32_bf16(a_, b_, d, 0, 0, 0)

__device__ __forceinline__ u16 f2bf(float f) {
  union { float f; uint32_t u; } a; a.f = f;
  uint32_t u = a.u;
  return (u16)((u + 0x7fffu + ((u >> 16) & 1u)) >> 16);
}
__device__ __forceinline__ float bf2f(u16 h) {
  union { uint32_t u; float f; } a; a.u = ((uint32_t)h) << 16;
  return a.f;
}

// ---------------- fused weight fp32 -> bf16 (contiguous dst) ----------------
__global__ __launch_bounds__(256) void wconv4(const float* __restrict__ a,
    const float* __restrict__ b, const float* __restrict__ c,
    const float* __restrict__ d, u16* __restrict__ out) {
  int i = blockIdx.x * 256 + threadIdx.x;
  const float* src; int off;
  if (i < 786432)       { src = a; off = i; }
  else if (i < 1048576) { src = b; off = i - 786432; }
  else if (i < 3145728) { src = c; off = i - 1048576; }
  else                  { src = d; off = i - 3145728; }
  out[i] = f2bf(src[off]);
}

// ---------------- LayerNorm (optionally fused shift+window gather) ----------------
template<bool WINDOW>
__global__ __launch_bounds__(256) void ln_win(const float* __restrict__ x,
    const float* __restrict__ gw, const float* __restrict__ bw,
    u16* __restrict__ out) {
  int wid = threadIdx.x >> 6;
  int lane = threadIdx.x & 63;
  int m = (blockIdx.x << 2) + wid;
  const float* src;
  if (WINDOW) {
    int n = m & 63;
    int bwin = m >> 6;
    int b = bwin >> 8;
    int wi = bwin & 255;
    int h = (((wi >> 4) << 3) + (n >> 3) + 4) & 127;
    int w = (((wi & 15) << 3) + (n & 7) + 4) & 127;
    src = x + (((size_t)((b << 7) + h) << 7) + (size_t)w) * 512;
  } else {
    src = x + ((size_t)m << 9);
  }
  int ch = lane << 3;
  float4 v0 = *(const float4*)(src + ch);
  float4 v1 = *(const float4*)(src + ch + 4);
  float vv[8] = {v0.x, v0.y, v0.z, v0.w, v1.x, v1.y, v1.z, v1.w};
  float s = 0.f, s2 = 0.f;
#pragma unroll
  for (int j = 0; j < 8; j++) { s += vv[j]; s2 += vv[j] * vv[j]; }
#pragma unroll
  for (int off = 32; off; off >>= 1) {
    s += __shfl_xor(s, off);
    s2 += __shfl_xor(s2, off);
  }
  float mean = s * (1.f / 512.f);
  float var = s2 * (1.f / 512.f) - mean * mean;
  float rstd = rsqrtf(var + 1e-5f);
  union { uint4 u; u16 h[8]; } pk;
#pragma unroll
  for (int j = 0; j < 8; j++)
    pk.h[j] = f2bf((vv[j] - mean) * rstd * gw[ch + j] + bw[ch + j]);
  *(uint4*)(out + ((size_t)m << 9) + ch) = pk.u;
}

// ---------------- 128x128-tile bf16 MFMA GEMM, 2 blocks/CU, counted vmcnt ---------
// 256 threads (4 waves, 2x2 of 64x64), BK=64, 64KB LDS double-buffer.
// Per K-tile: P0 {read A(8)+Bj01(4); stage A(s+2); PB; 16 MFMA; PB}
//             P1 {read Bj23(4);      stage B(s+2); PB; 16 MFMA; gate vmcnt(8); PB}
// EPI 0: qkv bf16 (+bias), ld=1536 | EPI 1: proj f32 scatter+resid | EPI 2: fc2 +=
// EPI 3: fc1 SwiGLU (BN=64 out; B-slot rows 0-63 = a, 64-127 = gate), ld=2048
template<int EPI, int K>
__global__ __launch_bounds__(256, 2) void gemm2p(
    const u16* __restrict__ A, const u16* __restrict__ Bw,
    const float* __restrict__ bias, void* __restrict__ outp,
    const float* __restrict__ resid, int NTN) {
  __shared__ __align__(16) u16 lds[2][2][8192];  // [buf][A,B][128*64]
  const int NT = K / 64;
  int bid = blockIdx.x;
  int nwg = gridDim.x;
  int wg = (bid & 7) * (nwg >> 3) + (bid >> 3);   // bijective XCD swizzle (nwg%8==0)
  int mt = wg / NTN, nt = wg - mt * NTN;
  int m0 = mt << 7;
  int n0 = (EPI == 3) ? (nt << 6) : (nt << 7);

  int tid = threadIdx.x;
  int wid = tid >> 6, lane = tid & 63;
  int wm = wid >> 1, wn = wid & 1;
  int l15 = lane & 15, lhi = lane >> 4;
  int swz = (lane & 7) << 4;

  int sr0 = tid >> 3;                              // 0..31
  int xk = (((tid & 7) ^ ((tid >> 3) & 7)) << 3);  // pre-swizzled source k-offset

  const u16* gAp = A + (size_t)(m0 + sr0) * K + xk;
  const u16* gB0p;  // B rows n0.. (a-rows for fc1)
  const u16* gB1p;  // fc1 gate rows
  gB0p = Bw + (size_t)(n0 + sr0) * K + xk;
  gB1p = (EPI == 3) ? (Bw + (size_t)(2048 + n0 + sr0) * K + xk) : (gB0p + (size_t)64 * K);

  // stage matrix (mat: 0=A, 1=B) of k-tile t: 4 x global_load_lds (32 rows each)
  auto stage = [&](int mat, int t) {
    if (t >= NT) return;
    u16* slot = &lds[t & 1][mat][0] + (wid << 9);  // + wave's 8-row offset
    if (mat == 0) {
      const u16* g = gAp + t * 64;
      GLD_LDS16(g, slot);
      GLD_LDS16(g + (size_t)32 * K, slot + 2048);
      GLD_LDS16(g + (size_t)64 * K, slot + 4096);
      GLD_LDS16(g + (size_t)96 * K, slot + 6144);
    } else if (EPI == 3) {
      const u16* ga = gB0p + t * 64;
      const u16* gg = gB1p + t * 64;
      GLD_LDS16(ga, slot);
      GLD_LDS16(ga + (size_t)32 * K, slot + 2048);
      GLD_LDS16(gg, slot + 4096);
      GLD_LDS16(gg + (size_t)32 * K, slot + 6144);
    } else {
      const u16* g = gB0p + t * 64;
      GLD_LDS16(g, slot);
      GLD_LDS16(g + (size_t)32 * K, slot + 2048);
      GLD_LDS16(g + (size_t)64 * K, slot + 4096);
      GLD_LDS16(g + (size_t)96 * K, slot + 6144);
    }
  };

  f32x4 acc[4][4] = {};   // [i][jj]  (fc1: jj<2 = a, jj>=2 = gate)
  bf16x8 afr[4][2], b0r[2][2], b1r[2][2];

  int aoffE = (wm * 64 + l15) * 64;
  int boffE = (EPI == 3) ? ((wn * 32 + l15) * 64) : ((wn * 64 + l15) * 64);
  int goffE = boffE + 4096;                        // fc1 gate rows (+64 rows)
  int k0e = ((lhi * 16) ^ swz) >> 1;
  int k1e = ((64 + lhi * 16) ^ swz) >> 1;

  // prologue: tiles 0,1 fully staged (A,B each); gate on tile 0 (oldest 8)
  stage(0, 0); stage(1, 0); stage(0, 1); stage(1, 1);
  asm volatile("s_waitcnt vmcnt(8)" ::: "memory");
  __builtin_amdgcn_sched_barrier(0);
  __builtin_amdgcn_s_barrier();
  __builtin_amdgcn_sched_barrier(0);

  for (int s = 0; s < NT; ++s) {
    const u16* Ah = &lds[s & 1][0][0];
    const u16* Bh = &lds[s & 1][1][0];

    // ---- phase 0: A x B(j0,j1); stage A(s+2) (A-slot reads done this phase)
#pragma unroll
    for (int i = 0; i < 4; i++) {
      afr[i][0] = *(const bf16x8*)&Ah[aoffE + i * 1024 + k0e];
      afr[i][1] = *(const bf16x8*)&Ah[aoffE + i * 1024 + k1e];
    }
#pragma unroll
    for (int j = 0; j < 2; j++) {
      b0r[j][0] = *(const bf16x8*)&Bh[boffE + j * 1024 + k0e];
      b0r[j][1] = *(const bf16x8*)&Bh[boffE + j * 1024 + k1e];
    }
    stage(0, s + 2);
    PB();
    __builtin_amdgcn_s_setprio(1);
#pragma unroll
    for (int i = 0; i < 4; i++)
#pragma unroll
      for (int j = 0; j < 2; j++) {
        ACCUM(acc[i][j], afr[i][0], b0r[j][0]);
        ACCUM(acc[i][j], afr[i][1], b0r[j][1]);
      }
    __builtin_amdgcn_s_setprio(0);
    PB();

    // ---- phase 1: A x B(j2,j3) [fc1: gate rows]; stage B(s+2)
#pragma unroll
    for (int j = 0; j < 2; j++) {
      int bo = (EPI == 3) ? (goffE + j * 1024) : (boffE + (2 + j) * 1024);
      b1r[j][0] = *(const bf16x8*)&Bh[bo + k0e];
      b1r[j][1] = *(const bf16x8*)&Bh[bo + k1e];
    }
    stage(1, s + 2);
    PB();
    __builtin_amdgcn_s_setprio(1);
#pragma unroll
    for (int i = 0; i < 4; i++)
#pragma unroll
      for (int j = 0; j < 2; j++) {
        ACCUM(acc[i][2 + j], afr[i][0], b1r[j][0]);
        ACCUM(acc[i][2 + j], afr[i][1], b1r[j][1]);
      }
    __builtin_amdgcn_s_setprio(0);
    // gate: oldest 8 outstanding = tile s+1 (A+B)
    if (s >= NT - 2) { asm volatile("s_waitcnt vmcnt(0)" ::: "memory"); }
    else             { asm volatile("s_waitcnt vmcnt(8)" ::: "memory"); }
    __builtin_amdgcn_sched_barrier(0);
    __builtin_amdgcn_s_barrier();
    __builtin_amdgcn_sched_barrier(0);
  }

  // ---------------- epilogue ----------------
#pragma unroll
  for (int i = 0; i < 4; i++) {
    int row = m0 + wm * 64 + i * 16 + lhi * 4;
    if (EPI == 0) {
      u16* out = (u16*)outp;
#pragma unroll
      for (int jj = 0; jj < 4; jj++) {
        int col = n0 + wn * 64 + jj * 16 + l15;
        float bv = bias[col];
#pragma unroll
        for (int rg = 0; rg < 4; rg++)
          out[(size_t)(row + rg) * 1536 + col] = f2bf(acc[i][jj][rg] + bv);
      }
    } else if (EPI == 1) {
      float* out = (float*)outp;
#pragma unroll
      for (int rg = 0; rg < 4; rg++) {
        int m = row + rg;
        int b = m >> 14, wi2 = (m >> 6) & 255, n = m & 63;
        int h = (((wi2 >> 4) << 3) + (n >> 3) + 4) & 127;
        int w = (((wi2 & 15) << 3) + (n & 7) + 4) & 127;
        size_t pix = (((size_t)((b << 7) + h) << 7) + (size_t)w) << 9;
#pragma unroll
        for (int jj = 0; jj < 4; jj++) {
          int col = n0 + wn * 64 + jj * 16 + l15;
          out[pix + col] = resid[pix + col] + acc[i][jj][rg] + bias[col];
        }
      }
    } else if (EPI == 2) {
      float* out = (float*)outp;
#pragma unroll
      for (int jj = 0; jj < 4; jj++) {
        int col = n0 + wn * 64 + jj * 16 + l15;
        float bv = bias[col];
#pragma unroll
        for (int rg = 0; rg < 4; rg++) {
          size_t idx = (size_t)(row + rg) * 512 + col;
          out[idx] = out[idx] + acc[i][jj][rg] + bv;
        }
      }
    } else {
      u16* out = (u16*)outp;
#pragma unroll
      for (int j = 0; j < 2; j++) {
        int col = n0 + wn * 32 + j * 16 + l15;
        float ba_ = bias[col], bg_ = bias[col + 2048];
#pragma unroll
        for (int rg = 0; rg < 4; rg++) {
          float av = acc[i][j][rg] + ba_;
          float gv = acc[i][2 + j][rg] + bg_;
          float sw = gv / (1.f + __expf(-gv));
          out[(size_t)(row + rg) * 2048 + col] = f2bf(sw * av);
        }
      }
    }
  }
}

// ---------------- MFMA windowed attention: 1 wave per (window, head) -------------
__global__ __launch_bounds__(256) void attn_mfma(
    const u16* __restrict__ qkv, u16* __restrict__ out) {
  __shared__ __align__(16) char alds[4][15360];
  int tid = threadIdx.x;
  int wid = tid >> 6, lane = tid & 63;
  int bwin = blockIdx.x >> 2;
  int head = ((blockIdx.x & 3) << 2) + wid;
  int wi = bwin & 255;
  int wr = wi >> 4, wc = wi & 15;
  char* Wb = alds[wid];
  u16* Qr = (u16*)Wb;                 // [64] rows, 40 u16 stride (80B)
  u16* Kr = (u16*)(Wb + 5120);
  u16* Vt = (u16*)(Wb + 10240);       // [32][72 u16] (144B stride)
  u16* PT = (u16*)Wb;                 // [64][72 u16] — overlaps Qr/Kr after S
  int t = lane;
  int l15 = lane & 15, lhi = lane >> 4;
  const u16* base = qkv + (size_t)((bwin << 6) + t) * 1536 + (head << 5);
  union U { uint4 u; u16 s[8]; };
  U vq[4], vk[4], vv[4];
#pragma unroll
  for (int g = 0; g < 4; g++) {
    vq[g].u = *(const uint4*)(base + (g << 3));
    vk[g].u = *(const uint4*)(base + 512 + (g << 3));
    vv[g].u = *(const uint4*)(base + 1024 + (g << 3));
  }
  float q[32], k[32];
#pragma unroll
  for (int j = 0; j < 32; j++) {
    q[j] = bf2f(vq[j >> 3].s[j & 7]);
    k[j] = bf2f(vk[j >> 3].s[j & 7]);
  }
  int r = t >> 3, c = t & 7;
#pragma unroll
  for (int d = 0; d < 16; d++) {
    float pos = (d < 8) ? (float)r : (float)c;
    int dd = (d < 8) ? d : d - 8;
    float ang = pos * __expf(-(float)dd * 1.1512925465f);  // 10000^(-dd/8)
    float sn, cs;
    __sincosf(ang, &sn, &cs);
    float q1 = q[d], q2 = q[d + 16];
    q[d] = q1 * cs - q2 * sn;  q[d + 16] = q2 * cs + q1 * sn;
    float k1 = k[d], k2 = k[d + 16];
    k[d] = k1 * cs - k2 * sn;  k[d + 16] = k2 * cs + k1 * sn;
  }
#pragma unroll
  for (int j = 0; j < 32; j++) q[j] *= 0.17677669529663687f;  // 32^-0.5
#pragma unroll
  for (int sl = 0; sl < 4; sl++) {
    U tq, tk;
#pragma unroll
    for (int j = 0; j < 8; j++) { tq.s[j] = f2bf(q[sl * 8 + j]); tk.s[j] = f2bf(k[sl * 8 + j]); }
    *(uint4*)(Qr + t * 40 + sl * 8) = tq.u;
    *(uint4*)(Kr + t * 40 + sl * 8) = tk.u;
  }
#pragma unroll
  for (int j = 0; j < 32; j++) Vt[j * 72 + t] = vv[j >> 3].s[j & 7];
  // ---- S^T = K · Q^T
  bf16x8 kf[4], qf[4];
#pragma unroll
  for (int i = 0; i < 4; i++) {
    kf[i] = *(const bf16x8*)(Kr + (i * 16 + l15) * 40 + lhi * 8);
    qf[i] = *(const bf16x8*)(Qr + (i * 16 + l15) * 40 + lhi * 8);
  }
  f32x4 zz = {0.f, 0.f, 0.f, 0.f};
  f32x4 st[4][4];
#pragma unroll
  for (int mi = 0; mi < 4; mi++)
#pragma unroll
    for (int nj = 0; nj < 4; nj++)
      st[mi][nj] = __builtin_amdgcn_mfma_f32_16x16x32_bf16(kf[mi], qf[nj], zz, 0, 0, 0);
  if (wr == 15 || wc == 15) {
    int idh = (wr == 15) ? ((r >= 4) ? 2 : 1) : 0;
    int idw = (wc == 15) ? ((c >= 4) ? 2 : 1) : 0;
    int code = idh * 3 + idw;
    int cq[4], cm[4][4];
#pragma unroll
    for (int nj = 0; nj < 4; nj++) cq[nj] = __shfl(code, nj * 16 + l15);
#pragma unroll
    for (int mi = 0; mi < 4; mi++)
#pragma unroll
      for (int rg = 0; rg < 4; rg++) cm[mi][rg] = __shfl(code, mi * 16 + lhi * 4 + rg);
#pragma unroll
    for (int mi = 0; mi < 4; mi++)
#pragma unroll
      for (int nj = 0; nj < 4; nj++)
#pragma unroll
        for (int rg = 0; rg < 4; rg++)
          if (cm[mi][rg] != cq[nj]) st[mi][nj][rg] -= 100.f;
  }
  float inv_[4];
#pragma unroll
  for (int nj = 0; nj < 4; nj++) {
    float mx = -1e30f;
#pragma unroll
    for (int mi = 0; mi < 4; mi++)
#pragma unroll
      for (int rg = 0; rg < 4; rg++) mx = fmaxf(mx, st[mi][nj][rg]);
    mx = fmaxf(mx, __shfl_xor(mx, 16));
    mx = fmaxf(mx, __shfl_xor(mx, 32));
    float sum = 0.f;
#pragma unroll
    for (int mi = 0; mi < 4; mi++)
#pragma unroll
      for (int rg = 0; rg < 4; rg++) {
        float p = __expf(st[mi][nj][rg] - mx);
        st[mi][nj][rg] = p;
        sum += p;
      }
    sum += __shfl_xor(sum, 16);
    sum += __shfl_xor(sum, 32);
    inv_[nj] = 1.f / sum;
  }
#pragma unroll
  for (int mi = 0; mi < 4; mi++)
#pragma unroll
    for (int nj = 0; nj < 4; nj++) {
      uint32_t lo, hi;
      asm("v_cvt_pk_bf16_f32 %0, %1, %2" : "=v"(lo) : "v"(st[mi][nj][0]), "v"(st[mi][nj][1]));
      asm("v_cvt_pk_bf16_f32 %0, %1, %2" : "=v"(hi) : "v"(st[mi][nj][2]), "v"(st[mi][nj][3]));
      uint2 pr; pr.x = lo; pr.y = hi;
      *(uint2*)(PT + (nj * 16 + l15) * 72 + mi * 16 + lhi * 4) = pr;
    }
  bf16x8 vf[2][2], pf[4][2];
#pragma unroll
  for (int i = 0; i < 2; i++)
#pragma unroll
    for (int kc = 0; kc < 2; kc++)
      vf[i][kc] = *(const bf16x8*)(Vt + (i * 16 + l15) * 72 + kc * 32 + lhi * 8);
#pragma unroll
  for (int nj = 0; nj < 4; nj++)
#pragma unroll
    for (int kc = 0; kc < 2; kc++)
      pf[nj][kc] = *(const bf16x8*)(PT + (nj * 16 + l15) * 72 + kc * 32 + lhi * 8);
#pragma unroll
  for (int i = 0; i < 2; i++)
#pragma unroll
    for (int nj = 0; nj < 4; nj++) {
      f32x4 o = __builtin_amdgcn_mfma_f32_16x16x32_bf16(vf[i][0], pf[nj][0], zz, 0, 0, 0);
      o = __builtin_amdgcn_mfma_f32_16x16x32_bf16(vf[i][1], pf[nj][1], o, 0, 0, 0);
      float iv = inv_[nj];
      float o0 = o[0] * iv, o1 = o[1] * iv, o2 = o[2] * iv, o3 = o[3] * iv;
      uint32_t lo, hi;
      asm("v_cvt_pk_bf16_f32 %0, %1, %2" : "=v"(lo) : "v"(o0), "v"(o1));
      asm("v_cvt_pk_bf16_f32 %0, %1, %2" : "=v"(hi) : "v"(o2), "v"(o3));
      uint2 pr; pr.x = lo; pr.y = hi;
      *(uint2*)(out + (size_t)((bwin << 6) + nj * 16 + l15) * 512 + (head << 5) + i * 16 + lhi * 4) = pr;
    }
}

// ---------------- launch ----------------
extern "C" void kernel_launch(void* const* d_in, const int* in_sizes, int n_in,
                              void* d_out, int out_size, void* d_ws, size_t ws_size,
                              hipStream_t stream) {
  (void)in_sizes; (void)n_in; (void)out_size; (void)ws_size;
  const float* x      = (const float*)d_in[0];
  const float* n1g    = (const float*)d_in[2];
  const float* n1b    = (const float*)d_in[3];
  const float* qkv_w  = (const float*)d_in[4];
  const float* qkv_b  = (const float*)d_in[5];
  const float* proj_w = (const float*)d_in[6];
  const float* proj_b = (const float*)d_in[7];
  const float* n2g    = (const float*)d_in[8];
  const float* n2b    = (const float*)d_in[9];
  const float* fc1_w  = (const float*)d_in[10];
  const float* fc1_b  = (const float*)d_in[11];
  const float* fc2_w  = (const float*)d_in[12];
  const float* fc2_b  = (const float*)d_in[13];

  char* ws = (char*)d_ws;
  u16* wb_qkv  = (u16*)ws;                  // 1536*512
  u16* wb_proj = wb_qkv + 786432;           // 512*512
  u16* wb_fc1  = wb_proj + 262144;          // 4096*512
  u16* wb_fc2  = wb_fc1 + 2097152;          // 512*2048
  u16* xw      = (u16*)(ws + 8388608);      // xw, later attnout
  u16* qkvb    = (u16*)(ws + 8388608 + 67108864);   // qkv, later y
  u16* yb      = qkvb;
  u16* hb      = (u16*)(ws + 8388608 + 134217728);  // h
  u16* attnout = xw;

  wconv4<<<16384, 256, 0, stream>>>(qkv_w, proj_w, fc1_w, fc2_w, wb_qkv);
  ln_win<true><<<16384, 256, 0, stream>>>(x, n1g, n1b, xw);
  gemm2p<0, 512><<<6144, 256, 0, stream>>>(xw, wb_qkv, qkv_b, qkvb, nullptr, 12);
  attn_mfma<<<4096, 256, 0, stream>>>(qkvb, attnout);
  gemm2p<1, 512><<<2048, 256, 0, stream>>>(attnout, wb_proj, proj_b, d_out, x, 4);
  ln_win<false><<<16384, 256, 0, stream>>>((const float*)d_out, n2g, n2b, yb);
  gemm2p<3, 512><<<16384, 256, 0, stream>>>(yb, wb_fc1, fc1_b, hb, nullptr, 32);
  gemm2p<2, 2048><<<2048, 256, 0, stream>>>(hb, wb_fc2, fc2_b, d_out, nullptr, 4);
}

// Round 9
// 805.612 us; speedup vs baseline: 1.2110x; 1.1014x over previous
//
#include <hip/hip_runtime.h>
#include <stdint.h>

typedef __attribute__((ext_vector_type(8))) short bf16x8;
typedef __attribute__((ext_vector_type(4))) float f32x4;
typedef unsigned short u16;

#define GLD_LDS16(g, l) __builtin_amdgcn_global_load_lds( \
    (const __attribute__((address_space(1))) void*)(g),   \
    (__attribute__((address_space(3))) void*)(l), 16, 0, 0)

#define PB() do { __builtin_amdgcn_sched_barrier(0); \
                  __builtin_amdgcn_s_barrier();      \
                  __builtin_amdgcn_sched_barrier(0); } while (0)

#define ACCUM(d, a_, b_) d = __builtin_amdgcn_mfma_f32_16x16x32_bf16(a_, b_, d, 0, 0, 0)

__device__ __forceinline__ u16 f2bf(float f) {
  union { float f; uint32_t u; } a; a.f = f;
  uint32_t u = a.u;
  return (u16)((u + 0x7fffu + ((u >> 16) & 1u)) >> 16);
}
__device__ __forceinline__ float bf2f(u16 h) {
  union { uint32_t u; float f; } a; a.u = ((uint32_t)h) << 16;
  return a.f;
}

// ---------------- LN1 (shift+window gather) fused with weight fp32->bf16 ----------
__global__ __launch_bounds__(256) void ln1_wconv(const float* __restrict__ x,
    const float* __restrict__ gw, const float* __restrict__ bw, u16* __restrict__ out,
    const float* __restrict__ qw, const float* __restrict__ pw,
    const float* __restrict__ f1w, const float* __restrict__ f2w,
    u16* __restrict__ wb) {
  int bx = blockIdx.x;
  if (bx >= 16384) {
    int i = (bx - 16384) * 256 + threadIdx.x;
    const float* src; int off;
    if (i < 786432)       { src = qw;  off = i; }
    else if (i < 1048576) { src = pw;  off = i - 786432; }
    else if (i < 3145728) { src = f1w; off = i - 1048576; }
    else                  { src = f2w; off = i - 3145728; }
    wb[i] = f2bf(src[off]);
    return;
  }
  int wid = threadIdx.x >> 6;
  int lane = threadIdx.x & 63;
  int m = (bx << 2) + wid;
  int n = m & 63;
  int bwin = m >> 6;
  int b = bwin >> 8;
  int wi = bwin & 255;
  int h = (((wi >> 4) << 3) + (n >> 3) + 4) & 127;
  int w = (((wi & 15) << 3) + (n & 7) + 4) & 127;
  const float* src = x + (((size_t)((b << 7) + h) << 7) + (size_t)w) * 512;
  int ch = lane << 3;
  float4 v0 = *(const float4*)(src + ch);
  float4 v1 = *(const float4*)(src + ch + 4);
  float vv[8] = {v0.x, v0.y, v0.z, v0.w, v1.x, v1.y, v1.z, v1.w};
  float s = 0.f, s2 = 0.f;
#pragma unroll
  for (int j = 0; j < 8; j++) { s += vv[j]; s2 += vv[j] * vv[j]; }
#pragma unroll
  for (int off = 32; off; off >>= 1) {
    s += __shfl_xor(s, off);
    s2 += __shfl_xor(s2, off);
  }
  float mean = s * (1.f / 512.f);
  float var = s2 * (1.f / 512.f) - mean * mean;
  float rstd = rsqrtf(var + 1e-5f);
  union { uint4 u; u16 hh[8]; } pk;
#pragma unroll
  for (int j = 0; j < 8; j++)
    pk.hh[j] = f2bf((vv[j] - mean) * rstd * gw[ch + j] + bw[ch + j]);
  *(uint4*)(out + ((size_t)m << 9) + ch) = pk.u;
}

// ---------------- LN2: bf16 input (s buffer), flat ----------------
__global__ __launch_bounds__(256) void ln2_bf16(const u16* __restrict__ sb,
    const float* __restrict__ gw, const float* __restrict__ bw,
    u16* __restrict__ out) {
  int wid = threadIdx.x >> 6;
  int lane = threadIdx.x & 63;
  int m = (blockIdx.x << 2) + wid;
  int ch = lane << 3;
  const u16* src = sb + ((size_t)m << 9) + ch;
  union { uint4 u; u16 hh[8]; } in;
  in.u = *(const uint4*)src;
  float vv[8];
#pragma unroll
  for (int j = 0; j < 8; j++) vv[j] = bf2f(in.hh[j]);
  float s = 0.f, s2 = 0.f;
#pragma unroll
  for (int j = 0; j < 8; j++) { s += vv[j]; s2 += vv[j] * vv[j]; }
#pragma unroll
  for (int off = 32; off; off >>= 1) {
    s += __shfl_xor(s, off);
    s2 += __shfl_xor(s2, off);
  }
  float mean = s * (1.f / 512.f);
  float var = s2 * (1.f / 512.f) - mean * mean;
  float rstd = rsqrtf(var + 1e-5f);
  union { uint4 u; u16 hh[8]; } pk;
#pragma unroll
  for (int j = 0; j < 8; j++)
    pk.hh[j] = f2bf((vv[j] - mean) * rstd * gw[ch + j] + bw[ch + j]);
  *(uint4*)(out + ((size_t)m << 9) + ch) = pk.u;
}

// ---------------- 256x256-tile 8-phase bf16 MFMA GEMM (B^T weights) ----------------
// (R4-proven engine; epilogues reworked for blocked qkv / bf16 residual diet)
// EPI 0: qkv  -> bf16 BLOCKED out [selhead][token][32] (+bias)
// EPI 1: proj -> bf16 s = resid(x) + acc + bias -> sb (window-reverse scatter)
// EPI 2: fc2  -> d_out fp32 = bf2f(sb) + acc + bias (single write)
// EPI 3: fc1  -> SwiGLU fused, BN=128 out, bf16, ld=2048
template<int EPI, int K>
__global__ __launch_bounds__(512, 1) void gemm8(
    const u16* __restrict__ A, const u16* __restrict__ Bw,
    const float* __restrict__ bias, void* __restrict__ outp,
    const float* __restrict__ resid, int NTN) {
  __shared__ __align__(16) u16 lds[2][4][8192];  // [buf][A0,A1,B0,B1][16KB]
  const int NT = K / 64;
  int bid = blockIdx.x;
  int nwg = gridDim.x;
  int wg = (bid & 7) * (nwg >> 3) + (bid >> 3);   // bijective XCD swizzle (nwg%8==0)
  int mt = wg / NTN, nt = wg - mt * NTN;
  int m0 = mt << 8;
  int n0 = (EPI == 3) ? (nt << 7) : (nt << 8);

  int tid = threadIdx.x;
  int wid = tid >> 6, lane = tid & 63;
  int wm = wid >> 2, wn = wid & 3;
  int l15 = lane & 15, lhi = lane >> 4;
  int swz = (lane & 7) << 4;

  int sr0 = tid >> 3;
  int xk = (((tid & 7) ^ ((tid >> 3) & 7)) << 3);  // pre-swizzled source k-offset

  auto stage = [&](int mat, int hh, int t) {
    if (t >= NT) return;
    u16* ld = &lds[t & 1][mat * 2 + hh][0] + (wid << 9);  // wave-uniform dest
    const u16* g0;
    if (mat == 0) {
      g0 = A + (size_t)(m0 + hh * 128 + sr0) * K + t * 64 + xk;
    } else {
      int rb;
      if (EPI == 3) rb = (hh ? 2048 : 0) + n0 + sr0;
      else          rb = n0 + hh * 128 + sr0;
      g0 = Bw + (size_t)rb * K + t * 64 + xk;
    }
    GLD_LDS16(g0, ld);
    GLD_LDS16(g0 + (size_t)64 * K, ld + 4096);
  };

  f32x4 acc[2][4][2][2] = {};   // [qm][i][qn][j]
  bf16x8 afr[4][2], b0r[2][2], b1r[2][2];

  int aoffE = (wm * 64 + l15) * 64;
  int boffE = (wn * 32 + l15) * 64;
  int k0e = ((lhi * 16) ^ swz) >> 1;
  int k1e = ((64 + lhi * 16) ^ swz) >> 1;

  stage(0, 0, 0); stage(1, 1, 0); stage(1, 0, 0); stage(0, 1, 0);
  stage(0, 0, 1); stage(1, 1, 1);
  asm volatile("s_waitcnt vmcnt(4)" ::: "memory");
  __builtin_amdgcn_sched_barrier(0);
  __builtin_amdgcn_s_barrier();
  __builtin_amdgcn_sched_barrier(0);

  for (int s = 0; s < NT; ++s) {
    const u16* Ah0 = &lds[s & 1][0][0];
    const u16* Ah1 = &lds[s & 1][1][0];
    const u16* Bh0 = &lds[s & 1][2][0];
    const u16* Bh1 = &lds[s & 1][3][0];

    // ---- phase 0: quadrant (A0,B0); stage B0(s+1)
#pragma unroll
    for (int i = 0; i < 4; i++) {
      afr[i][0] = *(const bf16x8*)&Ah0[aoffE + i * 1024 + k0e];
      afr[i][1] = *(const bf16x8*)&Ah0[aoffE + i * 1024 + k1e];
    }
#pragma unroll
    for (int j = 0; j < 2; j++) {
      b0r[j][0] = *(const bf16x8*)&Bh0[boffE + j * 1024 + k0e];
      b0r[j][1] = *(const bf16x8*)&Bh0[boffE + j * 1024 + k1e];
    }
    stage(1, 0, s + 1);
    PB();
    __builtin_amdgcn_s_setprio(1);
#pragma unroll
    for (int i = 0; i < 4; i++)
#pragma unroll
      for (int j = 0; j < 2; j++) {
        ACCUM(acc[0][i][0][j], afr[i][0], b0r[j][0]);
        ACCUM(acc[0][i][0][j], afr[i][1], b0r[j][1]);
      }
    __builtin_amdgcn_s_setprio(0);
    PB();

    // ---- phase 1: quadrant (A0,B1); stage A1(s+1)
#pragma unroll
    for (int j = 0; j < 2; j++) {
      b1r[j][0] = *(const bf16x8*)&Bh1[boffE + j * 1024 + k0e];
      b1r[j][1] = *(const bf16x8*)&Bh1[boffE + j * 1024 + k1e];
    }
    stage(0, 1, s + 1);
    PB();
    __builtin_amdgcn_s_setprio(1);
#pragma unroll
    for (int i = 0; i < 4; i++)
#pragma unroll
      for (int j = 0; j < 2; j++) {
        ACCUM(acc[0][i][1][j], afr[i][0], b1r[j][0]);
        ACCUM(acc[0][i][1][j], afr[i][1], b1r[j][1]);
      }
    __builtin_amdgcn_s_setprio(0);
    PB();

    // ---- phase 2: quadrant (A1,B1); stage A0(s+2)
#pragma unroll
    for (int i = 0; i < 4; i++) {
      afr[i][0] = *(const bf16x8*)&Ah1[aoffE + i * 1024 + k0e];
      afr[i][1] = *(const bf16x8*)&Ah1[aoffE + i * 1024 + k1e];
    }
    stage(0, 0, s + 2);
    PB();
    __builtin_amdgcn_s_setprio(1);
#pragma unroll
    for (int i = 0; i < 4; i++)
#pragma unroll
      for (int j = 0; j < 2; j++) {
        ACCUM(acc[1][i][1][j], afr[i][0], b1r[j][0]);
        ACCUM(acc[1][i][1][j], afr[i][1], b1r[j][1]);
      }
    __builtin_amdgcn_s_setprio(0);
    PB();

    // ---- phase 3: quadrant (A1,B0) (regs reused); stage B1(s+2)
    stage(1, 1, s + 2);
    PB();
    __builtin_amdgcn_s_setprio(1);
#pragma unroll
    for (int i = 0; i < 4; i++)
#pragma unroll
      for (int j = 0; j < 2; j++) {
        ACCUM(acc[1][i][0][j], afr[i][0], b0r[j][0]);
        ACCUM(acc[1][i][0][j], afr[i][1], b0r[j][1]);
      }
    __builtin_amdgcn_s_setprio(0);
    if (s >= NT - 2) { asm volatile("s_waitcnt vmcnt(0)" ::: "memory"); }
    else             { asm volatile("s_waitcnt vmcnt(4)" ::: "memory"); }
    __builtin_amdgcn_sched_barrier(0);
    __builtin_amdgcn_s_barrier();
    __builtin_amdgcn_sched_barrier(0);
  }

  // ---------------- epilogue ----------------
#pragma unroll
  for (int qm = 0; qm < 2; qm++)
#pragma unroll
    for (int i = 0; i < 4; i++) {
      int row = m0 + qm * 128 + wm * 64 + i * 16 + lhi * 4;
      if (EPI == 0) {
        // blocked qkv: out[(col>>5)][token][col&31]
        u16* out = (u16*)outp;
#pragma unroll
        for (int qn = 0; qn < 2; qn++)
#pragma unroll
          for (int j = 0; j < 2; j++) {
            int colb = n0 + qn * 128 + wn * 32 + j * 16;   // 16-aligned, no l15 carry
            int col = colb + l15;
            int sh = colb >> 5;
            int d = (colb & 31) + l15;
            float bv = bias[col];
#pragma unroll
            for (int rg = 0; rg < 4; rg++)
              out[(size_t)sh * 2097152 + (size_t)(row + rg) * 32 + d] =
                  f2bf(acc[qm][i][qn][j][rg] + bv);
          }
      } else if (EPI == 1) {
        u16* sbw = (u16*)outp;
#pragma unroll
        for (int rg = 0; rg < 4; rg++) {
          int m = row + rg;
          int b = m >> 14, wi2 = (m >> 6) & 255, n = m & 63;
          int h = (((wi2 >> 4) << 3) + (n >> 3) + 4) & 127;
          int w = (((wi2 & 15) << 3) + (n & 7) + 4) & 127;
          size_t pix = (((size_t)((b << 7) + h) << 7) + (size_t)w) << 9;
#pragma unroll
          for (int qn = 0; qn < 2; qn++)
#pragma unroll
            for (int j = 0; j < 2; j++) {
              int col = n0 + qn * 128 + wn * 32 + j * 16 + l15;
              sbw[pix + col] = f2bf(resid[pix + col] + acc[qm][i][qn][j][rg] + bias[col]);
            }
        }
      } else if (EPI == 2) {
        float* out = (float*)outp;
        const u16* sbp = (const u16*)resid;
#pragma unroll
        for (int qn = 0; qn < 2; qn++)
#pragma unroll
          for (int j = 0; j < 2; j++) {
            int col = n0 + qn * 128 + wn * 32 + j * 16 + l15;
            float bv = bias[col];
#pragma unroll
            for (int rg = 0; rg < 4; rg++) {
              size_t idx = (size_t)(row + rg) * 512 + col;
              out[idx] = bf2f(sbp[idx]) + acc[qm][i][qn][j][rg] + bv;
            }
          }
      } else {
        u16* out = (u16*)outp;
#pragma unroll
        for (int j = 0; j < 2; j++) {
          int col = n0 + wn * 32 + j * 16 + l15;
          float ba_ = bias[col], bg_ = bias[col + 2048];
#pragma unroll
          for (int rg = 0; rg < 4; rg++) {
            float av = acc[qm][i][0][j][rg] + ba_;
            float gv = acc[qm][i][1][j][rg] + bg_;
            float sw = gv / (1.f + __expf(-gv));
            out[(size_t)(row + rg) * 2048 + col] = f2bf(sw * av);
          }
        }
      }
    }
}

// ---------------- MFMA windowed attention (blocked qkv in, coalesced out) --------
__global__ __launch_bounds__(256) void attn_mfma(
    const u16* __restrict__ qkv, u16* __restrict__ out) {
  __shared__ __align__(16) char alds[4][15360];
  int tid = threadIdx.x;
  int wid = tid >> 6, lane = tid & 63;
  int bwin = blockIdx.x >> 2;
  int head = ((blockIdx.x & 3) << 2) + wid;
  int wi = bwin & 255;
  int wr = wi >> 4, wc = wi & 15;
  char* Wb = alds[wid];
  u16* Qr = (u16*)Wb;                 // [64] rows, 40 u16 stride (80B)
  u16* Kr = (u16*)(Wb + 5120);
  u16* Vt = (u16*)(Wb + 10240);       // [32][72 u16]
  u16* PT = (u16*)Wb;                 // [64][72 u16] — overlaps Qr/Kr after S
  int t = lane;
  int l15 = lane & 15, lhi = lane >> 4;
  size_t tok = (size_t)(bwin << 6) + t;
  const u16* qb = qkv + (size_t)head * 2097152 + tok * 32;
  union U { uint4 u; u16 s[8]; };
  U vq[4], vk[4], vv[4];
#pragma unroll
  for (int g = 0; g < 4; g++) {
    vq[g].u = *(const uint4*)(qb + (g << 3));
    vk[g].u = *(const uint4*)(qb + 33554432 + (g << 3));
    vv[g].u = *(const uint4*)(qb + 67108864 + (g << 3));
  }
  float q[32], k[32];
#pragma unroll
  for (int j = 0; j < 32; j++) {
    q[j] = bf2f(vq[j >> 3].s[j & 7]);
    k[j] = bf2f(vk[j >> 3].s[j & 7]);
  }
  int r = t >> 3, c = t & 7;
#pragma unroll
  for (int d = 0; d < 16; d++) {
    float pos = (d < 8) ? (float)r : (float)c;
    int dd = (d < 8) ? d : d - 8;
    float ang = pos * __expf(-(float)dd * 1.1512925465f);  // 10000^(-dd/8)
    float sn, cs;
    __sincosf(ang, &sn, &cs);
    float q1 = q[d], q2 = q[d + 16];
    q[d] = q1 * cs - q2 * sn;  q[d + 16] = q2 * cs + q1 * sn;
    float k1 = k[d], k2 = k[d + 16];
    k[d] = k1 * cs - k2 * sn;  k[d + 16] = k2 * cs + k1 * sn;
  }
#pragma unroll
  for (int j = 0; j < 32; j++) q[j] *= 0.17677669529663687f;  // 32^-0.5
#pragma unroll
  for (int sl = 0; sl < 4; sl++) {
    U tq, tk;
#pragma unroll
    for (int j = 0; j < 8; j++) { tq.s[j] = f2bf(q[sl * 8 + j]); tk.s[j] = f2bf(k[sl * 8 + j]); }
    *(uint4*)(Qr + t * 40 + sl * 8) = tq.u;
    *(uint4*)(Kr + t * 40 + sl * 8) = tk.u;
  }
#pragma unroll
  for (int j = 0; j < 32; j++) Vt[j * 72 + t] = vv[j >> 3].s[j & 7];
  // ---- S^T = K · Q^T
  bf16x8 kf[4], qf[4];
#pragma unroll
  for (int i = 0; i < 4; i++) {
    kf[i] = *(const bf16x8*)(Kr + (i * 16 + l15) * 40 + lhi * 8);
    qf[i] = *(const bf16x8*)(Qr + (i * 16 + l15) * 40 + lhi * 8);
  }
  f32x4 zz = {0.f, 0.f, 0.f, 0.f};
  f32x4 st[4][4];
#pragma unroll
  for (int mi = 0; mi < 4; mi++)
#pragma unroll
    for (int nj = 0; nj < 4; nj++)
      st[mi][nj] = __builtin_amdgcn_mfma_f32_16x16x32_bf16(kf[mi], qf[nj], zz, 0, 0, 0);
  if (wr == 15 || wc == 15) {
    int idh = (wr == 15) ? ((r >= 4) ? 2 : 1) : 0;
    int idw = (wc == 15) ? ((c >= 4) ? 2 : 1) : 0;
    int code = idh * 3 + idw;
    int cq[4], cm[4][4];
#pragma unroll
    for (int nj = 0; nj < 4; nj++) cq[nj] = __shfl(code, nj * 16 + l15);
#pragma unroll
    for (int mi = 0; mi < 4; mi++)
#pragma unroll
      for (int rg = 0; rg < 4; rg++) cm[mi][rg] = __shfl(code, mi * 16 + lhi * 4 + rg);
#pragma unroll
    for (int mi = 0; mi < 4; mi++)
#pragma unroll
      for (int nj = 0; nj < 4; nj++)
#pragma unroll
        for (int rg = 0; rg < 4; rg++)
          if (cm[mi][rg] != cq[nj]) st[mi][nj][rg] -= 100.f;
  }
  float inv_[4];
#pragma unroll
  for (int nj = 0; nj < 4; nj++) {
    float mx = -1e30f;
#pragma unroll
    for (int mi = 0; mi < 4; mi++)
#pragma unroll
      for (int rg = 0; rg < 4; rg++) mx = fmaxf(mx, st[mi][nj][rg]);
    mx = fmaxf(mx, __shfl_xor(mx, 16));
    mx = fmaxf(mx, __shfl_xor(mx, 32));
    float sum = 0.f;
#pragma unroll
    for (int mi = 0; mi < 4; mi++)
#pragma unroll
      for (int rg = 0; rg < 4; rg++) {
        float p = __expf(st[mi][nj][rg] - mx);
        st[mi][nj][rg] = p;
        sum += p;
      }
    sum += __shfl_xor(sum, 16);
    sum += __shfl_xor(sum, 32);
    inv_[nj] = 1.f / sum;
  }
#pragma unroll
  for (int mi = 0; mi < 4; mi++)
#pragma unroll
    for (int nj = 0; nj < 4; nj++) {
      uint32_t lo, hi;
      asm("v_cvt_pk_bf16_f32 %0, %1, %2" : "=v"(lo) : "v"(st[mi][nj][0]), "v"(st[mi][nj][1]));
      asm("v_cvt_pk_bf16_f32 %0, %1, %2" : "=v"(hi) : "v"(st[mi][nj][2]), "v"(st[mi][nj][3]));
      uint2 pr; pr.x = lo; pr.y = hi;
      *(uint2*)(PT + (nj * 16 + l15) * 72 + mi * 16 + lhi * 4) = pr;
    }
  bf16x8 vf[2][2], pf[4][2];
#pragma unroll
  for (int i = 0; i < 2; i++)
#pragma unroll
    for (int kc = 0; kc < 2; kc++)
      vf[i][kc] = *(const bf16x8*)(Vt + (i * 16 + l15) * 72 + kc * 32 + lhi * 8);
#pragma unroll
  for (int nj = 0; nj < 4; nj++)
#pragma unroll
    for (int kc = 0; kc < 2; kc++)
      pf[nj][kc] = *(const bf16x8*)(PT + (nj * 16 + l15) * 72 + kc * 32 + lhi * 8);
  // O^T tiles -> wave-private LDS [64 tok][36 u16] then coalesced global stores
  u16* Ot = (u16*)Wb;   // all prior LDS reads consumed (may-alias keeps order)
#pragma unroll
  for (int i = 0; i < 2; i++)
#pragma unroll
    for (int nj = 0; nj < 4; nj++) {
      f32x4 o = __builtin_amdgcn_mfma_f32_16x16x32_bf16(vf[i][0], pf[nj][0], zz, 0, 0, 0);
      o = __builtin_amdgcn_mfma_f32_16x16x32_bf16(vf[i][1], pf[nj][1], o, 0, 0, 0);
      float iv = inv_[nj];
      float o0 = o[0] * iv, o1 = o[1] * iv, o2 = o[2] * iv, o3 = o[3] * iv;
      uint32_t lo, hi;
      asm("v_cvt_pk_bf16_f32 %0, %1, %2" : "=v"(lo) : "v"(o0), "v"(o1));
      asm("v_cvt_pk_bf16_f32 %0, %1, %2" : "=v"(hi) : "v"(o2), "v"(o3));
      uint2 pr; pr.x = lo; pr.y = hi;
      *(uint2*)(Ot + (nj * 16 + l15) * 36 + i * 16 + lhi * 4) = pr;
    }
#pragma unroll
  for (int g = 0; g < 4; g++) {
    int tl = g * 16 + (lane >> 2);
    int ch_ = (lane & 3) << 3;
    uint4 v = *(const uint4*)(Ot + tl * 36 + ch_);
    *(uint4*)(out + (size_t)((bwin << 6) + tl) * 512 + (head << 5) + ch_) = v;
  }
}

// ---------------- launch ----------------
extern "C" void kernel_launch(void* const* d_in, const int* in_sizes, int n_in,
                              void* d_out, int out_size, void* d_ws, size_t ws_size,
                              hipStream_t stream) {
  (void)in_sizes; (void)n_in; (void)out_size; (void)ws_size;
  const float* x      = (const float*)d_in[0];
  const float* n1g    = (const float*)d_in[2];
  const float* n1b    = (const float*)d_in[3];
  const float* qkv_w  = (const float*)d_in[4];
  const float* qkv_b  = (const float*)d_in[5];
  const float* proj_w = (const float*)d_in[6];
  const float* proj_b = (const float*)d_in[7];
  const float* n2g    = (const float*)d_in[8];
  const float* n2b    = (const float*)d_in[9];
  const float* fc1_w  = (const float*)d_in[10];
  const float* fc1_b  = (const float*)d_in[11];
  const float* fc2_w  = (const float*)d_in[12];
  const float* fc2_b  = (const float*)d_in[13];

  const size_t MB = 1048576ULL;
  char* ws = (char*)d_ws;
  u16* wb_qkv  = (u16*)ws;                  // [0,8MB)
  u16* wb_proj = wb_qkv + 786432;
  u16* wb_fc1  = wb_proj + 262144;
  u16* wb_fc2  = wb_fc1 + 2097152;
  u16* xw      = (u16*)(ws + 8 * MB);       // [8,72)   LN1 out; later attnout
  u16* qkvb    = (u16*)(ws + 72 * MB);      // [72,264) blocked qkv
  u16* attnout = xw;                        // [8,72)   (xw dead after qkv GEMM)
  u16* hb      = (u16*)(ws + 8 * MB);       // [8,264)  fc1 out (qkv/attnout dead)
  u16* sb      = (u16*)(ws + 264 * MB);     // [264,328) bf16 residual s = x+attn
  u16* yb      = (u16*)(ws + 328 * MB);     // [328,392) LN2 out

  ln1_wconv<<<32768, 256, 0, stream>>>(x, n1g, n1b, xw,
                                       qkv_w, proj_w, fc1_w, fc2_w, wb_qkv);
  gemm8<0, 512><<<1536, 512, 0, stream>>>(xw, wb_qkv, qkv_b, qkvb, nullptr, 6);
  attn_mfma<<<4096, 256, 0, stream>>>(qkvb, attnout);
  gemm8<1, 512><<<512, 512, 0, stream>>>(attnout, wb_proj, proj_b, sb, x, 2);
  ln2_bf16<<<16384, 256, 0, stream>>>(sb, n2g, n2b, yb);
  gemm8<3, 512><<<4096, 512, 0, stream>>>(yb, wb_fc1, fc1_b, hb, nullptr, 16);
  gemm8<2, 2048><<<512, 512, 0, stream>>>(hb, wb_fc2, fc2_b, d_out, (const float*)sb, 2);
}

// Round 10
// 804.518 us; speedup vs baseline: 1.2127x; 1.0014x over previous
//
#include <hip/hip_runtime.h>
#include <stdint.h>

typedef __attribute__((ext_vector_type(8))) short bf16x8;
typedef __attribute__((ext_vector_type(4))) float f32x4;
typedef unsigned short u16;

#define GLD_LDS16(g, l) __builtin_amdgcn_global_load_lds( \
    (const __attribute__((address_space(1))) void*)(g),   \
    (__attribute__((address_space(3))) void*)(l), 16, 0, 0)

#define PB() do { __builtin_amdgcn_sched_barrier(0); \
                  __builtin_amdgcn_s_barrier();      \
                  __builtin_amdgcn_sched_barrier(0); } while (0)

#define ACCUM(d, a_, b_) d = __builtin_amdgcn_mfma_f32_16x16x32_bf16(a_, b_, d, 0, 0, 0)

__device__ __forceinline__ u16 f2bf(float f) {
  union { float f; uint32_t u; } a; a.f = f;
  uint32_t u = a.u;
  return (u16)((u + 0x7fffu + ((u >> 16) & 1u)) >> 16);
}
__device__ __forceinline__ float bf2f(u16 h) {
  union { uint32_t u; float f; } a; a.u = ((uint32_t)h) << 16;
  return a.f;
}

// ---------------- LN1 (shift+window gather) fused with weight fp32->bf16 ----------
__global__ __launch_bounds__(256) void ln1_wconv(const float* __restrict__ x,
    const float* __restrict__ gw, const float* __restrict__ bw, u16* __restrict__ out,
    const float* __restrict__ qw, const float* __restrict__ pw,
    const float* __restrict__ f1w, const float* __restrict__ f2w,
    u16* __restrict__ wb) {
  int bx = blockIdx.x;
  if (bx >= 16384) {
    int i = (bx - 16384) * 256 + threadIdx.x;
    const float* src; int off;
    if (i < 786432)       { src = qw;  off = i; }
    else if (i < 1048576) { src = pw;  off = i - 786432; }
    else if (i < 3145728) { src = f1w; off = i - 1048576; }
    else                  { src = f2w; off = i - 3145728; }
    wb[i] = f2bf(src[off]);
    return;
  }
  int wid = threadIdx.x >> 6;
  int lane = threadIdx.x & 63;
  int m = (bx << 2) + wid;
  int n = m & 63;
  int bwin = m >> 6;
  int b = bwin >> 8;
  int wi = bwin & 255;
  int h = (((wi >> 4) << 3) + (n >> 3) + 4) & 127;
  int w = (((wi & 15) << 3) + (n & 7) + 4) & 127;
  const float* src = x + (((size_t)((b << 7) + h) << 7) + (size_t)w) * 512;
  int ch = lane << 3;
  float4 v0 = *(const float4*)(src + ch);
  float4 v1 = *(const float4*)(src + ch + 4);
  float vv[8] = {v0.x, v0.y, v0.z, v0.w, v1.x, v1.y, v1.z, v1.w};
  float s = 0.f, s2 = 0.f;
#pragma unroll
  for (int j = 0; j < 8; j++) { s += vv[j]; s2 += vv[j] * vv[j]; }
#pragma unroll
  for (int off = 32; off; off >>= 1) {
    s += __shfl_xor(s, off);
    s2 += __shfl_xor(s2, off);
  }
  float mean = s * (1.f / 512.f);
  float var = s2 * (1.f / 512.f) - mean * mean;
  float rstd = rsqrtf(var + 1e-5f);
  union { uint4 u; u16 hh[8]; } pk;
#pragma unroll
  for (int j = 0; j < 8; j++)
    pk.hh[j] = f2bf((vv[j] - mean) * rstd * gw[ch + j] + bw[ch + j]);
  *(uint4*)(out + ((size_t)m << 9) + ch) = pk.u;
}

// ---------------- LN2: bf16 input (s buffer), flat ----------------
__global__ __launch_bounds__(256) void ln2_bf16(const u16* __restrict__ sb,
    const float* __restrict__ gw, const float* __restrict__ bw,
    u16* __restrict__ out) {
  int wid = threadIdx.x >> 6;
  int lane = threadIdx.x & 63;
  int m = (blockIdx.x << 2) + wid;
  int ch = lane << 3;
  const u16* src = sb + ((size_t)m << 9) + ch;
  union { uint4 u; u16 hh[8]; } in;
  in.u = *(const uint4*)src;
  float vv[8];
#pragma unroll
  for (int j = 0; j < 8; j++) vv[j] = bf2f(in.hh[j]);
  float s = 0.f, s2 = 0.f;
#pragma unroll
  for (int j = 0; j < 8; j++) { s += vv[j]; s2 += vv[j] * vv[j]; }
#pragma unroll
  for (int off = 32; off; off >>= 1) {
    s += __shfl_xor(s, off);
    s2 += __shfl_xor(s2, off);
  }
  float mean = s * (1.f / 512.f);
  float var = s2 * (1.f / 512.f) - mean * mean;
  float rstd = rsqrtf(var + 1e-5f);
  union { uint4 u; u16 hh[8]; } pk;
#pragma unroll
  for (int j = 0; j < 8; j++)
    pk.hh[j] = f2bf((vv[j] - mean) * rstd * gw[ch + j] + bw[ch + j]);
  *(uint4*)(out + ((size_t)m << 9) + ch) = pk.u;
}

// ---------------- 256x256-tile 8-phase bf16 MFMA GEMM, read-balanced 8/4/8/4 ------
// P3 of tile s pre-reads B0(s+1) frags (b0n regs, parity-swapped); publish gate for
// B0(s+1) moved to end-P2 (vmcnt(4)+barrier). End-P3 gate vmcnt(4) drains A1(s+1).
// EPI 0: qkv  -> bf16 BLOCKED out [selhead][token][32] (+bias)
// EPI 1: proj -> bf16 s = resid(x) + acc + bias -> sb (window-reverse scatter)
// EPI 2: fc2  -> d_out fp32 = bf2f(sb) + acc + bias (single write)
// EPI 3: fc1  -> SwiGLU fused, BN=128 out, bf16, ld=2048
template<int EPI, int K>
__global__ __launch_bounds__(512, 1) void gemm8(
    const u16* __restrict__ A, const u16* __restrict__ Bw,
    const float* __restrict__ bias, void* __restrict__ outp,
    const float* __restrict__ resid, int NTN) {
  __shared__ __align__(16) u16 lds[2][4][8192];  // [buf][A0,A1,B0,B1][16KB]
  const int NT = K / 64;
  int bid = blockIdx.x;
  int nwg = gridDim.x;
  int wg = (bid & 7) * (nwg >> 3) + (bid >> 3);   // bijective XCD swizzle (nwg%8==0)
  int mt = wg / NTN, nt = wg - mt * NTN;
  int m0 = mt << 8;
  int n0 = (EPI == 3) ? (nt << 7) : (nt << 8);

  int tid = threadIdx.x;
  int wid = tid >> 6, lane = tid & 63;
  int wm = wid >> 2, wn = wid & 3;
  int l15 = lane & 15, lhi = lane >> 4;
  int swz = (lane & 7) << 4;

  int sr0 = tid >> 3;
  int xk = (((tid & 7) ^ ((tid >> 3) & 7)) << 3);  // pre-swizzled source k-offset

  auto stage = [&](int mat, int hh, int t) {
    if (t >= NT) return;
    u16* ld = &lds[t & 1][mat * 2 + hh][0] + (wid << 9);  // wave-uniform dest
    const u16* g0;
    if (mat == 0) {
      g0 = A + (size_t)(m0 + hh * 128 + sr0) * K + t * 64 + xk;
    } else {
      int rb;
      if (EPI == 3) rb = (hh ? 2048 : 0) + n0 + sr0;
      else          rb = n0 + hh * 128 + sr0;
      g0 = Bw + (size_t)rb * K + t * 64 + xk;
    }
    GLD_LDS16(g0, ld);
    GLD_LDS16(g0 + (size_t)64 * K, ld + 4096);
  };

  f32x4 acc[2][4][2][2] = {};   // [qm][i][qn][j]
  bf16x8 afr[4][2], b1r[2][2];
  bf16x8 b0A[2][2], b0B[2][2];  // parity-swapped B0 fragment sets

  int aoffE = (wm * 64 + l15) * 64;
  int boffE = (wn * 32 + l15) * 64;
  int k0e = ((lhi * 16) ^ swz) >> 1;
  int k1e = ((64 + lhi * 16) ^ swz) >> 1;

  // prologue: tile0 all slots + tile1 {A0,B1}; drain tile0; pre-read B0(0) frags
  stage(0, 0, 0); stage(1, 1, 0); stage(1, 0, 0); stage(0, 1, 0);
  stage(0, 0, 1); stage(1, 1, 1);
  asm volatile("s_waitcnt vmcnt(4)" ::: "memory");
  __builtin_amdgcn_sched_barrier(0);
  __builtin_amdgcn_s_barrier();
  __builtin_amdgcn_sched_barrier(0);
  {
    const u16* B00 = &lds[0][2][0];
#pragma unroll
    for (int j = 0; j < 2; j++) {
      b0A[j][0] = *(const bf16x8*)&B00[boffE + j * 1024 + k0e];
      b0A[j][1] = *(const bf16x8*)&B00[boffE + j * 1024 + k1e];
    }
  }

  auto tile = [&](int s, bf16x8 (&b0c)[2][2], bf16x8 (&b0n)[2][2]) {
    const u16* Ah0 = &lds[s & 1][0][0];
    const u16* Ah1 = &lds[s & 1][1][0];
    const u16* Bh1 = &lds[s & 1][3][0];
    const u16* Bn0 = &lds[(s + 1) & 1][2][0];

    // ---- P0: read A0 (8); stage B0(s+1); MFMA (A0 x B0cur)
#pragma unroll
    for (int i = 0; i < 4; i++) {
      afr[i][0] = *(const bf16x8*)&Ah0[aoffE + i * 1024 + k0e];
      afr[i][1] = *(const bf16x8*)&Ah0[aoffE + i * 1024 + k1e];
    }
    stage(1, 0, s + 1);
    PB();
    __builtin_amdgcn_s_setprio(1);
#pragma unroll
    for (int i = 0; i < 4; i++)
#pragma unroll
      for (int j = 0; j < 2; j++) {
        ACCUM(acc[0][i][0][j], afr[i][0], b0c[j][0]);
        ACCUM(acc[0][i][0][j], afr[i][1], b0c[j][1]);
      }
    __builtin_amdgcn_s_setprio(0);
    PB();

    // ---- P1: read B1 (4); stage A1(s+1); MFMA (A0 x B1)
#pragma unroll
    for (int j = 0; j < 2; j++) {
      b1r[j][0] = *(const bf16x8*)&Bh1[boffE + j * 1024 + k0e];
      b1r[j][1] = *(const bf16x8*)&Bh1[boffE + j * 1024 + k1e];
    }
    stage(0, 1, s + 1);
    PB();
    __builtin_amdgcn_s_setprio(1);
#pragma unroll
    for (int i = 0; i < 4; i++)
#pragma unroll
      for (int j = 0; j < 2; j++) {
        ACCUM(acc[0][i][1][j], afr[i][0], b1r[j][0]);
        ACCUM(acc[0][i][1][j], afr[i][1], b1r[j][1]);
      }
    __builtin_amdgcn_s_setprio(0);
    PB();

    // ---- P2: read A1 (8); stage A0(s+2); MFMA (A1 x B1); gate B0(s+1)
#pragma unroll
    for (int i = 0; i < 4; i++) {
      afr[i][0] = *(const bf16x8*)&Ah1[aoffE + i * 1024 + k0e];
      afr[i][1] = *(const bf16x8*)&Ah1[aoffE + i * 1024 + k1e];
    }
    stage(0, 0, s + 2);
    PB();
    __builtin_amdgcn_s_setprio(1);
#pragma unroll
    for (int i = 0; i < 4; i++)
#pragma unroll
      for (int j = 0; j < 2; j++) {
        ACCUM(acc[1][i][1][j], afr[i][0], b1r[j][0]);
        ACCUM(acc[1][i][1][j], afr[i][1], b1r[j][1]);
      }
    __builtin_amdgcn_s_setprio(0);
    if (s < NT - 2)       { asm volatile("s_waitcnt vmcnt(4)" ::: "memory"); }
    else if (s == NT - 2) { asm volatile("s_waitcnt vmcnt(2)" ::: "memory"); }
    __builtin_amdgcn_sched_barrier(0);
    __builtin_amdgcn_s_barrier();
    __builtin_amdgcn_sched_barrier(0);

    // ---- P3: read B0(s+1) frags (4, cross-buffer); stage B1(s+2); MFMA (A1 x B0cur)
    if (s < NT - 1) {
#pragma unroll
      for (int j = 0; j < 2; j++) {
        b0n[j][0] = *(const bf16x8*)&Bn0[boffE + j * 1024 + k0e];
        b0n[j][1] = *(const bf16x8*)&Bn0[boffE + j * 1024 + k1e];
      }
    }
    stage(1, 1, s + 2);
    PB();
    __builtin_amdgcn_s_setprio(1);
#pragma unroll
    for (int i = 0; i < 4; i++)
#pragma unroll
      for (int j = 0; j < 2; j++) {
        ACCUM(acc[1][i][0][j], afr[i][0], b0c[j][0]);
        ACCUM(acc[1][i][0][j], afr[i][1], b0c[j][1]);
      }
    __builtin_amdgcn_s_setprio(0);
    if (s >= NT - 2) { asm volatile("s_waitcnt vmcnt(0)" ::: "memory"); }
    else             { asm volatile("s_waitcnt vmcnt(4)" ::: "memory"); }
    __builtin_amdgcn_sched_barrier(0);
    __builtin_amdgcn_s_barrier();
    __builtin_amdgcn_sched_barrier(0);
  };

  for (int sp = 0; sp < NT; sp += 2) {
    tile(sp, b0A, b0B);
    tile(sp + 1, b0B, b0A);
  }

  // ---------------- epilogue ----------------
#pragma unroll
  for (int qm = 0; qm < 2; qm++)
#pragma unroll
    for (int i = 0; i < 4; i++) {
      int row = m0 + qm * 128 + wm * 64 + i * 16 + lhi * 4;
      if (EPI == 0) {
        u16* out = (u16*)outp;
#pragma unroll
        for (int qn = 0; qn < 2; qn++)
#pragma unroll
          for (int j = 0; j < 2; j++) {
            int colb = n0 + qn * 128 + wn * 32 + j * 16;
            int col = colb + l15;
            int sh = colb >> 5;
            int d = (colb & 31) + l15;
            float bv = bias[col];
#pragma unroll
            for (int rg = 0; rg < 4; rg++)
              out[(size_t)sh * 2097152 + (size_t)(row + rg) * 32 + d] =
                  f2bf(acc[qm][i][qn][j][rg] + bv);
          }
      } else if (EPI == 1) {
        u16* sbw = (u16*)outp;
#pragma unroll
        for (int rg = 0; rg < 4; rg++) {
          int m = row + rg;
          int b = m >> 14, wi2 = (m >> 6) & 255, n = m & 63;
          int h = (((wi2 >> 4) << 3) + (n >> 3) + 4) & 127;
          int w = (((wi2 & 15) << 3) + (n & 7) + 4) & 127;
          size_t pix = (((size_t)((b << 7) + h) << 7) + (size_t)w) << 9;
#pragma unroll
          for (int qn = 0; qn < 2; qn++)
#pragma unroll
            for (int j = 0; j < 2; j++) {
              int col = n0 + qn * 128 + wn * 32 + j * 16 + l15;
              sbw[pix + col] = f2bf(resid[pix + col] + acc[qm][i][qn][j][rg] + bias[col]);
            }
        }
      } else if (EPI == 2) {
        float* out = (float*)outp;
        const u16* sbp = (const u16*)resid;
#pragma unroll
        for (int qn = 0; qn < 2; qn++)
#pragma unroll
          for (int j = 0; j < 2; j++) {
            int col = n0 + qn * 128 + wn * 32 + j * 16 + l15;
            float bv = bias[col];
#pragma unroll
            for (int rg = 0; rg < 4; rg++) {
              size_t idx = (size_t)(row + rg) * 512 + col;
              out[idx] = bf2f(sbp[idx]) + acc[qm][i][qn][j][rg] + bv;
            }
          }
      } else {
        u16* out = (u16*)outp;
#pragma unroll
        for (int j = 0; j < 2; j++) {
          int col = n0 + wn * 32 + j * 16 + l15;
          float ba_ = bias[col], bg_ = bias[col + 2048];
#pragma unroll
          for (int rg = 0; rg < 4; rg++) {
            float av = acc[qm][i][0][j][rg] + ba_;
            float gv = acc[qm][i][1][j][rg] + bg_;
            float sw = gv / (1.f + __expf(-gv));
            out[(size_t)(row + rg) * 2048 + col] = f2bf(sw * av);
          }
        }
      }
    }
}

// ---------------- MFMA windowed attention (blocked qkv in, coalesced out) --------
__global__ __launch_bounds__(256) void attn_mfma(
    const u16* __restrict__ qkv, u16* __restrict__ out) {
  __shared__ __align__(16) char alds[4][15360];
  int tid = threadIdx.x;
  int wid = tid >> 6, lane = tid & 63;
  int bwin = blockIdx.x >> 2;
  int head = ((blockIdx.x & 3) << 2) + wid;
  int wi = bwin & 255;
  int wr = wi >> 4, wc = wi & 15;
  char* Wb = alds[wid];
  u16* Qr = (u16*)Wb;
  u16* Kr = (u16*)(Wb + 5120);
  u16* Vt = (u16*)(Wb + 10240);
  u16* PT = (u16*)Wb;
  int t = lane;
  int l15 = lane & 15, lhi = lane >> 4;
  size_t tok = (size_t)(bwin << 6) + t;
  const u16* qb = qkv + (size_t)head * 2097152 + tok * 32;
  union U { uint4 u; u16 s[8]; };
  U vq[4], vk[4], vv[4];
#pragma unroll
  for (int g = 0; g < 4; g++) {
    vq[g].u = *(const uint4*)(qb + (g << 3));
    vk[g].u = *(const uint4*)(qb + 33554432 + (g << 3));
    vv[g].u = *(const uint4*)(qb + 67108864 + (g << 3));
  }
  float q[32], k[32];
#pragma unroll
  for (int j = 0; j < 32; j++) {
    q[j] = bf2f(vq[j >> 3].s[j & 7]);
    k[j] = bf2f(vk[j >> 3].s[j & 7]);
  }
  int r = t >> 3, c = t & 7;
#pragma unroll
  for (int d = 0; d < 16; d++) {
    float pos = (d < 8) ? (float)r : (float)c;
    int dd = (d < 8) ? d : d - 8;
    float ang = pos * __expf(-(float)dd * 1.1512925465f);
    float sn, cs;
    __sincosf(ang, &sn, &cs);
    float q1 = q[d], q2 = q[d + 16];
    q[d] = q1 * cs - q2 * sn;  q[d + 16] = q2 * cs + q1 * sn;
    float k1 = k[d], k2 = k[d + 16];
    k[d] = k1 * cs - k2 * sn;  k[d + 16] = k2 * cs + k1 * sn;
  }
#pragma unroll
  for (int j = 0; j < 32; j++) q[j] *= 0.17677669529663687f;
#pragma unroll
  for (int sl = 0; sl < 4; sl++) {
    U tq, tk;
#pragma unroll
    for (int j = 0; j < 8; j++) { tq.s[j] = f2bf(q[sl * 8 + j]); tk.s[j] = f2bf(k[sl * 8 + j]); }
    *(uint4*)(Qr + t * 40 + sl * 8) = tq.u;
    *(uint4*)(Kr + t * 40 + sl * 8) = tk.u;
  }
#pragma unroll
  for (int j = 0; j < 32; j++) Vt[j * 72 + t] = vv[j >> 3].s[j & 7];
  bf16x8 kf[4], qf[4];
#pragma unroll
  for (int i = 0; i < 4; i++) {
    kf[i] = *(const bf16x8*)(Kr + (i * 16 + l15) * 40 + lhi * 8);
    qf[i] = *(const bf16x8*)(Qr + (i * 16 + l15) * 40 + lhi * 8);
  }
  f32x4 zz = {0.f, 0.f, 0.f, 0.f};
  f32x4 st[4][4];
#pragma unroll
  for (int mi = 0; mi < 4; mi++)
#pragma unroll
    for (int nj = 0; nj < 4; nj++)
      st[mi][nj] = __builtin_amdgcn_mfma_f32_16x16x32_bf16(kf[mi], qf[nj], zz, 0, 0, 0);
  if (wr == 15 || wc == 15) {
    int idh = (wr == 15) ? ((r >= 4) ? 2 : 1) : 0;
    int idw = (wc == 15) ? ((c >= 4) ? 2 : 1) : 0;
    int code = idh * 3 + idw;
    int cq[4], cm[4][4];
#pragma unroll
    for (int nj = 0; nj < 4; nj++) cq[nj] = __shfl(code, nj * 16 + l15);
#pragma unroll
    for (int mi = 0; mi < 4; mi++)
#pragma unroll
      for (int rg = 0; rg < 4; rg++) cm[mi][rg] = __shfl(code, mi * 16 + lhi * 4 + rg);
#pragma unroll
    for (int mi = 0; mi < 4; mi++)
#pragma unroll
      for (int nj = 0; nj < 4; nj++)
#pragma unroll
        for (int rg = 0; rg < 4; rg++)
          if (cm[mi][rg] != cq[nj]) st[mi][nj][rg] -= 100.f;
  }
  float inv_[4];
#pragma unroll
  for (int nj = 0; nj < 4; nj++) {
    float mx = -1e30f;
#pragma unroll
    for (int mi = 0; mi < 4; mi++)
#pragma unroll
      for (int rg = 0; rg < 4; rg++) mx = fmaxf(mx, st[mi][nj][rg]);
    mx = fmaxf(mx, __shfl_xor(mx, 16));
    mx = fmaxf(mx, __shfl_xor(mx, 32));
    float sum = 0.f;
#pragma unroll
    for (int mi = 0; mi < 4; mi++)
#pragma unroll
      for (int rg = 0; rg < 4; rg++) {
        float p = __expf(st[mi][nj][rg] - mx);
        st[mi][nj][rg] = p;
        sum += p;
      }
    sum += __shfl_xor(sum, 16);
    sum += __shfl_xor(sum, 32);
    inv_[nj] = 1.f / sum;
  }
#pragma unroll
  for (int mi = 0; mi < 4; mi++)
#pragma unroll
    for (int nj = 0; nj < 4; nj++) {
      uint32_t lo, hi;
      asm("v_cvt_pk_bf16_f32 %0, %1, %2" : "=v"(lo) : "v"(st[mi][nj][0]), "v"(st[mi][nj][1]));
      asm("v_cvt_pk_bf16_f32 %0, %1, %2" : "=v"(hi) : "v"(st[mi][nj][2]), "v"(st[mi][nj][3]));
      uint2 pr; pr.x = lo; pr.y = hi;
      *(uint2*)(PT + (nj * 16 + l15) * 72 + mi * 16 + lhi * 4) = pr;
    }
  bf16x8 vf[2][2], pf[4][2];
#pragma unroll
  for (int i = 0; i < 2; i++)
#pragma unroll
    for (int kc = 0; kc < 2; kc++)
      vf[i][kc] = *(const bf16x8*)(Vt + (i * 16 + l15) * 72 + kc * 32 + lhi * 8);
#pragma unroll
  for (int nj = 0; nj < 4; nj++)
#pragma unroll
    for (int kc = 0; kc < 2; kc++)
      pf[nj][kc] = *(const bf16x8*)(PT + (nj * 16 + l15) * 72 + kc * 32 + lhi * 8);
  u16* Ot = (u16*)Wb;
#pragma unroll
  for (int i = 0; i < 2; i++)
#pragma unroll
    for (int nj = 0; nj < 4; nj++) {
      f32x4 o = __builtin_amdgcn_mfma_f32_16x16x32_bf16(vf[i][0], pf[nj][0], zz, 0, 0, 0);
      o = __builtin_amdgcn_mfma_f32_16x16x32_bf16(vf[i][1], pf[nj][1], o, 0, 0, 0);
      float iv = inv_[nj];
      float o0 = o[0] * iv, o1 = o[1] * iv, o2 = o[2] * iv, o3 = o[3] * iv;
      uint32_t lo, hi;
      asm("v_cvt_pk_bf16_f32 %0, %1, %2" : "=v"(lo) : "v"(o0), "v"(o1));
      asm("v_cvt_pk_bf16_f32 %0, %1, %2" : "=v"(hi) : "v"(o2), "v"(o3));
      uint2 pr; pr.x = lo; pr.y = hi;
      *(uint2*)(Ot + (nj * 16 + l15) * 36 + i * 16 + lhi * 4) = pr;
    }
#pragma unroll
  for (int g = 0; g < 4; g++) {
    int tl = g * 16 + (lane >> 2);
    int ch_ = (lane & 3) << 3;
    uint4 v = *(const uint4*)(Ot + tl * 36 + ch_);
    *(uint4*)(out + (size_t)((bwin << 6) + tl) * 512 + (head << 5) + ch_) = v;
  }
}

// ---------------- launch ----------------
extern "C" void kernel_launch(void* const* d_in, const int* in_sizes, int n_in,
                              void* d_out, int out_size, void* d_ws, size_t ws_size,
                              hipStream_t stream) {
  (void)in_sizes; (void)n_in; (void)out_size; (void)ws_size;
  const float* x      = (const float*)d_in[0];
  const float* n1g    = (const float*)d_in[2];
  const float* n1b    = (const float*)d_in[3];
  const float* qkv_w  = (const float*)d_in[4];
  const float* qkv_b  = (const float*)d_in[5];
  const float* proj_w = (const float*)d_in[6];
  const float* proj_b = (const float*)d_in[7];
  const float* n2g    = (const float*)d_in[8];
  const float* n2b    = (const float*)d_in[9];
  const float* fc1_w  = (const float*)d_in[10];
  const float* fc1_b  = (const float*)d_in[11];
  const float* fc2_w  = (const float*)d_in[12];
  const float* fc2_b  = (const float*)d_in[13];

  const size_t MB = 1048576ULL;
  char* ws = (char*)d_ws;
  u16* wb_qkv  = (u16*)ws;
  u16* wb_proj = wb_qkv + 786432;
  u16* wb_fc1  = wb_proj + 262144;
  u16* wb_fc2  = wb_fc1 + 2097152;
  u16* xw      = (u16*)(ws + 8 * MB);
  u16* qkvb    = (u16*)(ws + 72 * MB);
  u16* attnout = xw;
  u16* hb      = (u16*)(ws + 8 * MB);
  u16* sb      = (u16*)(ws + 264 * MB);
  u16* yb      = (u16*)(ws + 328 * MB);

  ln1_wconv<<<32768, 256, 0, stream>>>(x, n1g, n1b, xw,
                                       qkv_w, proj_w, fc1_w, fc2_w, wb_qkv);
  gemm8<0, 512><<<1536, 512, 0, stream>>>(xw, wb_qkv, qkv_b, qkvb, nullptr, 6);
  attn_mfma<<<4096, 256, 0, stream>>>(qkvb, attnout);
  gemm8<1, 512><<<512, 512, 0, stream>>>(attnout, wb_proj, proj_b, sb, x, 2);
  ln2_bf16<<<16384, 256, 0, stream>>>(sb, n2g, n2b, yb);
  gemm8<3, 512><<<4096, 512, 0, stream>>>(yb, wb_fc1, fc1_b, hb, nullptr, 16);
  gemm8<2, 2048><<<512, 512, 0, stream>>>(hb, wb_fc2, fc2_b, d_out, (const float*)sb, 2);
}

// Round 11
// 641.941 us; speedup vs baseline: 1.5198x; 1.2533x over previous
//
#include <hip/hip_runtime.h>
#include <stdint.h>

typedef __attribute__((ext_vector_type(8))) short bf16x8;
typedef __attribute__((ext_vector_type(4))) float f32x4;
typedef __attribute__((ext_vector_type(4))) int i32x4;
typedef unsigned short u16;

#define GLD_LDS16(g, l) __builtin_amdgcn_global_load_lds( \
    (const __attribute__((address_space(1))) void*)(g),   \
    (__attribute__((address_space(3))) void*)(l), 16, 0, 0)

#define PB() do { __builtin_amdgcn_sched_barrier(0); \
                  __builtin_amdgcn_s_barrier();      \
                  __builtin_amdgcn_sched_barrier(0); } while (0)

#define ACCUM(d, a_, b_) d = __builtin_amdgcn_mfma_f32_16x16x32_bf16(a_, b_, d, 0, 0, 0)
#define ACCI(d, a_, b_)  d = __builtin_amdgcn_mfma_i32_16x16x64_i8(a_, b_, d, 0, 0, 0)

#define INV_A (1.0f / 16384.0f)   // act x16, w x1024
#define INV_P (1.0f / 32768.0f)   // attn x32, w x1024

__device__ __forceinline__ u16 f2bf(float f) {
  union { float f; uint32_t u; } a; a.f = f;
  uint32_t u = a.u;
  return (u16)((u + 0x7fffu + ((u >> 16) & 1u)) >> 16);
}
__device__ __forceinline__ float bf2f(u16 h) {
  union { uint32_t u; float f; } a; a.u = ((uint32_t)h) << 16;
  return a.f;
}
__device__ __forceinline__ uint32_t q8x4(float a, float b, float c, float d, float s) {
  int qa = (int)rintf(fminf(fmaxf(a * s, -127.f), 127.f));
  int qb = (int)rintf(fminf(fmaxf(b * s, -127.f), 127.f));
  int qc = (int)rintf(fminf(fmaxf(c * s, -127.f), 127.f));
  int qd = (int)rintf(fminf(fmaxf(d * s, -127.f), 127.f));
  return (qa & 255) | ((qb & 255) << 8) | ((qc & 255) << 16) | ((qd & 255) << 24);
}

// ---------------- LN1 (shift+window gather, i8 out) + weight conversions ----------
__global__ __launch_bounds__(256) void ln1_wconv(const float* __restrict__ x,
    const float* __restrict__ gw, const float* __restrict__ bw, char* __restrict__ out,
    const float* __restrict__ qw, const float* __restrict__ pw,
    const float* __restrict__ f1w, const float* __restrict__ f2w,
    char* __restrict__ wb8, u16* __restrict__ wfc2) {
  int bx = blockIdx.x;
  if (bx >= 16384) {
    if (bx < 16384 + 3072) {
      // i8 weights: qkv | proj | fc1, x1024, 4 per thread
      int i4 = (bx - 16384) * 1024 + threadIdx.x * 4;
      float w[4];
#pragma unroll
      for (int j = 0; j < 4; j++) {
        int idx = i4 + j;
        if (idx < 786432)        w[j] = qw[idx];
        else if (idx < 1048576)  w[j] = pw[idx - 786432];
        else                     w[j] = f1w[idx - 1048576];
      }
      *(uint32_t*)(wb8 + i4) = q8x4(w[0], w[1], w[2], w[3], 1024.f);
    } else {
      // fc2 bf16 weights, 2 per thread
      int i2 = (bx - 16384 - 3072) * 512 + threadIdx.x * 2;
      uint32_t pk = (uint32_t)f2bf(f2w[i2]) | ((uint32_t)f2bf(f2w[i2 + 1]) << 16);
      *(uint32_t*)(wfc2 + i2) = pk;
    }
    return;
  }
  int wid = threadIdx.x >> 6;
  int lane = threadIdx.x & 63;
  int m = (bx << 2) + wid;
  int n = m & 63;
  int bwin = m >> 6;
  int b = bwin >> 8;
  int wi = bwin & 255;
  int h = (((wi >> 4) << 3) + (n >> 3) + 4) & 127;
  int w = (((wi & 15) << 3) + (n & 7) + 4) & 127;
  const float* src = x + (((size_t)((b << 7) + h) << 7) + (size_t)w) * 512;
  int ch = lane << 3;
  float4 v0 = *(const float4*)(src + ch);
  float4 v1 = *(const float4*)(src + ch + 4);
  float vv[8] = {v0.x, v0.y, v0.z, v0.w, v1.x, v1.y, v1.z, v1.w};
  float s = 0.f, s2 = 0.f;
#pragma unroll
  for (int j = 0; j < 8; j++) { s += vv[j]; s2 += vv[j] * vv[j]; }
#pragma unroll
  for (int off = 32; off; off >>= 1) {
    s += __shfl_xor(s, off);
    s2 += __shfl_xor(s2, off);
  }
  float mean = s * (1.f / 512.f);
  float var = s2 * (1.f / 512.f) - mean * mean;
  float rstd = rsqrtf(var + 1e-5f);
  float y[8];
#pragma unroll
  for (int j = 0; j < 8; j++) y[j] = (vv[j] - mean) * rstd * gw[ch + j] + bw[ch + j];
  uint2 o;
  o.x = q8x4(y[0], y[1], y[2], y[3], 16.f);
  o.y = q8x4(y[4], y[5], y[6], y[7], 16.f);
  *(uint2*)(out + ((size_t)m << 9) + ch) = o;
}

// ---------------- LN2: bf16 residual in -> i8 out ----------------
__global__ __launch_bounds__(256) void ln2_q8(const u16* __restrict__ sb,
    const float* __restrict__ gw, const float* __restrict__ bw,
    char* __restrict__ out) {
  int wid = threadIdx.x >> 6;
  int lane = threadIdx.x & 63;
  int m = (blockIdx.x << 2) + wid;
  int ch = lane << 3;
  union { uint4 u; u16 hh[8]; } in;
  in.u = *(const uint4*)(sb + ((size_t)m << 9) + ch);
  float vv[8];
#pragma unroll
  for (int j = 0; j < 8; j++) vv[j] = bf2f(in.hh[j]);
  float s = 0.f, s2 = 0.f;
#pragma unroll
  for (int j = 0; j < 8; j++) { s += vv[j]; s2 += vv[j] * vv[j]; }
#pragma unroll
  for (int off = 32; off; off >>= 1) {
    s += __shfl_xor(s, off);
    s2 += __shfl_xor(s2, off);
  }
  float mean = s * (1.f / 512.f);
  float var = s2 * (1.f / 512.f) - mean * mean;
  float rstd = rsqrtf(var + 1e-5f);
  float y[8];
#pragma unroll
  for (int j = 0; j < 8; j++) y[j] = (vv[j] - mean) * rstd * gw[ch + j] + bw[ch + j];
  uint2 o;
  o.x = q8x4(y[0], y[1], y[2], y[3], 16.f);
  o.y = q8x4(y[4], y[5], y[6], y[7], 16.f);
  *(uint2*)(out + ((size_t)m << 9) + ch) = o;
}

// ---------------- i8 256x256-tile GEMM, K=512 (NT=4, K-tile=128 i8) ---------------
// Same R10 phase engine; mfma_i32_16x16x64_i8; i32 acc; dequant in epilogue.
// EPI 0: qkv -> bf16 BLOCKED [selhead][token][32] (+bias), INV_A
// EPI 1: proj -> bf16 s = x + acc*INV_P + bias (window-reverse scatter)
// EPI 3: fc1 -> SwiGLU fused, bf16 h out, ld=2048, INV_A
template<int EPI>
__global__ __launch_bounds__(512, 1) void gemm8i(
    const char* __restrict__ A, const char* __restrict__ Bw,
    const float* __restrict__ bias, void* __restrict__ outp,
    const float* __restrict__ resid, int NTN) {
  __shared__ __align__(16) char lds[2][4][16384];  // [buf][A0,A1,B0,B1][128r x 128B]
  const int K = 512, NT = 4;
  int bid = blockIdx.x;
  int nwg = gridDim.x;
  int wg = (bid & 7) * (nwg >> 3) + (bid >> 3);
  int mt = wg / NTN, nt = wg - mt * NTN;
  int m0 = mt << 8;
  int n0 = (EPI == 3) ? (nt << 7) : (nt << 8);

  int tid = threadIdx.x;
  int wid = tid >> 6, lane = tid & 63;
  int wm = wid >> 2, wn = wid & 3;
  int l15 = lane & 15, lhi = lane >> 4;
  int swz = (lane & 7) << 4;

  int sr0 = tid >> 3;                               // 0..63
  int xk = (((tid & 7) ^ ((tid >> 3) & 7)) << 4);   // pre-swizzled source byte offset

  auto stage = [&](int mat, int hh, int t) {
    if (t >= NT) return;
    char* ld = &lds[t & 1][mat * 2 + hh][0] + (wid << 10);
    const char* g0;
    if (mat == 0) {
      g0 = A + (size_t)(m0 + hh * 128 + sr0) * K + t * 128 + xk;
    } else {
      int rb;
      if (EPI == 3) rb = (hh ? 2048 : 0) + n0 + sr0;
      else          rb = n0 + hh * 128 + sr0;
      g0 = Bw + (size_t)rb * K + t * 128 + xk;
    }
    GLD_LDS16(g0, ld);
    GLD_LDS16(g0 + (size_t)64 * K, ld + 8192);
  };

  i32x4 acc[2][4][2][2] = {};
  i32x4 afr[4][2], b1r[2][2];
  i32x4 b0A[2][2], b0B[2][2];

  int aoffB = (wm * 64 + l15) * 128;
  int boffB = (wn * 32 + l15) * 128;
  int k0b = (lhi * 16) ^ swz;
  int k1b = (64 + lhi * 16) ^ swz;

  stage(0, 0, 0); stage(1, 1, 0); stage(1, 0, 0); stage(0, 1, 0);
  stage(0, 0, 1); stage(1, 1, 1);
  asm volatile("s_waitcnt vmcnt(4)" ::: "memory");
  __builtin_amdgcn_sched_barrier(0);
  __builtin_amdgcn_s_barrier();
  __builtin_amdgcn_sched_barrier(0);
  {
    const char* B00 = &lds[0][2][0];
#pragma unroll
    for (int j = 0; j < 2; j++) {
      b0A[j][0] = *(const i32x4*)&B00[boffB + j * 2048 + k0b];
      b0A[j][1] = *(const i32x4*)&B00[boffB + j * 2048 + k1b];
    }
  }

  auto tile = [&](int s, i32x4 (&b0c)[2][2], i32x4 (&b0n)[2][2]) {
    const char* Ah0 = &lds[s & 1][0][0];
    const char* Ah1 = &lds[s & 1][1][0];
    const char* Bh1 = &lds[s & 1][3][0];
    const char* Bn0 = &lds[(s + 1) & 1][2][0];

    // ---- P0: read A0 (8); stage B0(s+1); MFMA (A0 x B0cur)
#pragma unroll
    for (int i = 0; i < 4; i++) {
      afr[i][0] = *(const i32x4*)&Ah0[aoffB + i * 2048 + k0b];
      afr[i][1] = *(const i32x4*)&Ah0[aoffB + i * 2048 + k1b];
    }
    stage(1, 0, s + 1);
    PB();
    __builtin_amdgcn_s_setprio(1);
#pragma unroll
    for (int i = 0; i < 4; i++)
#pragma unroll
      for (int j = 0; j < 2; j++) {
        ACCI(acc[0][i][0][j], afr[i][0], b0c[j][0]);
        ACCI(acc[0][i][0][j], afr[i][1], b0c[j][1]);
      }
    __builtin_amdgcn_s_setprio(0);
    PB();

    // ---- P1: read B1 (4); stage A1(s+1); MFMA (A0 x B1)
#pragma unroll
    for (int j = 0; j < 2; j++) {
      b1r[j][0] = *(const i32x4*)&Bh1[boffB + j * 2048 + k0b];
      b1r[j][1] = *(const i32x4*)&Bh1[boffB + j * 2048 + k1b];
    }
    stage(0, 1, s + 1);
    PB();
    __builtin_amdgcn_s_setprio(1);
#pragma unroll
    for (int i = 0; i < 4; i++)
#pragma unroll
      for (int j = 0; j < 2; j++) {
        ACCI(acc[0][i][1][j], afr[i][0], b1r[j][0]);
        ACCI(acc[0][i][1][j], afr[i][1], b1r[j][1]);
      }
    __builtin_amdgcn_s_setprio(0);
    PB();

    // ---- P2: read A1 (8); stage A0(s+2); MFMA (A1 x B1); gate B0(s+1)
#pragma unroll
    for (int i = 0; i < 4; i++) {
      afr[i][0] = *(const i32x4*)&Ah1[aoffB + i * 2048 + k0b];
      afr[i][1] = *(const i32x4*)&Ah1[aoffB + i * 2048 + k1b];
    }
    stage(0, 0, s + 2);
    PB();
    __builtin_amdgcn_s_setprio(1);
#pragma unroll
    for (int i = 0; i < 4; i++)
#pragma unroll
      for (int j = 0; j < 2; j++) {
        ACCI(acc[1][i][1][j], afr[i][0], b1r[j][0]);
        ACCI(acc[1][i][1][j], afr[i][1], b1r[j][1]);
      }
    __builtin_amdgcn_s_setprio(0);
    if (s < NT - 2)       { asm volatile("s_waitcnt vmcnt(4)" ::: "memory"); }
    else if (s == NT - 2) { asm volatile("s_waitcnt vmcnt(2)" ::: "memory"); }
    __builtin_amdgcn_sched_barrier(0);
    __builtin_amdgcn_s_barrier();
    __builtin_amdgcn_sched_barrier(0);

    // ---- P3: read B0(s+1) (4, cross-buffer); stage B1(s+2); MFMA (A1 x B0cur)
    if (s < NT - 1) {
#pragma unroll
      for (int j = 0; j < 2; j++) {
        b0n[j][0] = *(const i32x4*)&Bn0[boffB + j * 2048 + k0b];
        b0n[j][1] = *(const i32x4*)&Bn0[boffB + j * 2048 + k1b];
      }
    }
    stage(1, 1, s + 2);
    PB();
    __builtin_amdgcn_s_setprio(1);
#pragma unroll
    for (int i = 0; i < 4; i++)
#pragma unroll
      for (int j = 0; j < 2; j++) {
        ACCI(acc[1][i][0][j], afr[i][0], b0c[j][0]);
        ACCI(acc[1][i][0][j], afr[i][1], b0c[j][1]);
      }
    __builtin_amdgcn_s_setprio(0);
    if (s >= NT - 2) { asm volatile("s_waitcnt vmcnt(0)" ::: "memory"); }
    else             { asm volatile("s_waitcnt vmcnt(4)" ::: "memory"); }
    __builtin_amdgcn_sched_barrier(0);
    __builtin_amdgcn_s_barrier();
    __builtin_amdgcn_sched_barrier(0);
  };

  for (int sp = 0; sp < NT; sp += 2) {
    tile(sp, b0A, b0B);
    tile(sp + 1, b0B, b0A);
  }

  // ---------------- epilogue (dequant) ----------------
#pragma unroll
  for (int qm = 0; qm < 2; qm++)
#pragma unroll
    for (int i = 0; i < 4; i++) {
      int row = m0 + qm * 128 + wm * 64 + i * 16 + lhi * 4;
      if (EPI == 0) {
        u16* out = (u16*)outp;
#pragma unroll
        for (int qn = 0; qn < 2; qn++)
#pragma unroll
          for (int j = 0; j < 2; j++) {
            int colb = n0 + qn * 128 + wn * 32 + j * 16;
            int col = colb + l15;
            int sh = colb >> 5;
            int d = (colb & 31) + l15;
            float bv = bias[col];
#pragma unroll
            for (int rg = 0; rg < 4; rg++)
              out[(size_t)sh * 2097152 + (size_t)(row + rg) * 32 + d] =
                  f2bf((float)acc[qm][i][qn][j][rg] * INV_A + bv);
          }
      } else if (EPI == 1) {
        u16* sbw = (u16*)outp;
#pragma unroll
        for (int rg = 0; rg < 4; rg++) {
          int m = row + rg;
          int b = m >> 14, wi2 = (m >> 6) & 255, n = m & 63;
          int h = (((wi2 >> 4) << 3) + (n >> 3) + 4) & 127;
          int w = (((wi2 & 15) << 3) + (n & 7) + 4) & 127;
          size_t pix = (((size_t)((b << 7) + h) << 7) + (size_t)w) << 9;
#pragma unroll
          for (int qn = 0; qn < 2; qn++)
#pragma unroll
            for (int j = 0; j < 2; j++) {
              int col = n0 + qn * 128 + wn * 32 + j * 16 + l15;
              sbw[pix + col] = f2bf(resid[pix + col] +
                                    (float)acc[qm][i][qn][j][rg] * INV_P + bias[col]);
            }
        }
      } else {
        u16* out = (u16*)outp;
#pragma unroll
        for (int j = 0; j < 2; j++) {
          int col = n0 + wn * 32 + j * 16 + l15;
          float ba_ = bias[col], bg_ = bias[col + 2048];
#pragma unroll
          for (int rg = 0; rg < 4; rg++) {
            float av = (float)acc[qm][i][0][j][rg] * INV_A + ba_;
            float gv = (float)acc[qm][i][1][j][rg] * INV_A + bg_;
            float sw = gv / (1.f + __expf(-gv));
            out[(size_t)(row + rg) * 2048 + col] = f2bf(sw * av);
          }
        }
      }
    }
}

// ---------------- bf16 256x256-tile GEMM (fc2 only: K=2048, += residual) ----------
template<int EPI, int K>
__global__ __launch_bounds__(512, 1) void gemm8(
    const u16* __restrict__ A, const u16* __restrict__ Bw,
    const float* __restrict__ bias, void* __restrict__ outp,
    const float* __restrict__ resid, int NTN) {
  __shared__ __align__(16) u16 lds[2][4][8192];
  const int NT = K / 64;
  int bid = blockIdx.x;
  int nwg = gridDim.x;
  int wg = (bid & 7) * (nwg >> 3) + (bid >> 3);
  int mt = wg / NTN, nt = wg - mt * NTN;
  int m0 = mt << 8;
  int n0 = nt << 8;

  int tid = threadIdx.x;
  int wid = tid >> 6, lane = tid & 63;
  int wm = wid >> 2, wn = wid & 3;
  int l15 = lane & 15, lhi = lane >> 4;
  int swz = (lane & 7) << 4;

  int sr0 = tid >> 3;
  int xk = (((tid & 7) ^ ((tid >> 3) & 7)) << 3);

  auto stage = [&](int mat, int hh, int t) {
    if (t >= NT) return;
    u16* ld = &lds[t & 1][mat * 2 + hh][0] + (wid << 9);
    const u16* g0;
    if (mat == 0) g0 = A + (size_t)(m0 + hh * 128 + sr0) * K + t * 64 + xk;
    else          g0 = Bw + (size_t)(n0 + hh * 128 + sr0) * K + t * 64 + xk;
    GLD_LDS16(g0, ld);
    GLD_LDS16(g0 + (size_t)64 * K, ld + 4096);
  };

  f32x4 acc[2][4][2][2] = {};
  bf16x8 afr[4][2], b1r[2][2];
  bf16x8 b0A[2][2], b0B[2][2];

  int aoffE = (wm * 64 + l15) * 64;
  int boffE = (wn * 32 + l15) * 64;
  int k0e = ((lhi * 16) ^ swz) >> 1;
  int k1e = ((64 + lhi * 16) ^ swz) >> 1;

  stage(0, 0, 0); stage(1, 1, 0); stage(1, 0, 0); stage(0, 1, 0);
  stage(0, 0, 1); stage(1, 1, 1);
  asm volatile("s_waitcnt vmcnt(4)" ::: "memory");
  __builtin_amdgcn_sched_barrier(0);
  __builtin_amdgcn_s_barrier();
  __builtin_amdgcn_sched_barrier(0);
  {
    const u16* B00 = &lds[0][2][0];
#pragma unroll
    for (int j = 0; j < 2; j++) {
      b0A[j][0] = *(const bf16x8*)&B00[boffE + j * 1024 + k0e];
      b0A[j][1] = *(const bf16x8*)&B00[boffE + j * 1024 + k1e];
    }
  }

  auto tile = [&](int s, bf16x8 (&b0c)[2][2], bf16x8 (&b0n)[2][2]) {
    const u16* Ah0 = &lds[s & 1][0][0];
    const u16* Ah1 = &lds[s & 1][1][0];
    const u16* Bh1 = &lds[s & 1][3][0];
    const u16* Bn0 = &lds[(s + 1) & 1][2][0];

#pragma unroll
    for (int i = 0; i < 4; i++) {
      afr[i][0] = *(const bf16x8*)&Ah0[aoffE + i * 1024 + k0e];
      afr[i][1] = *(const bf16x8*)&Ah0[aoffE + i * 1024 + k1e];
    }
    stage(1, 0, s + 1);
    PB();
    __builtin_amdgcn_s_setprio(1);
#pragma unroll
    for (int i = 0; i < 4; i++)
#pragma unroll
      for (int j = 0; j < 2; j++) {
        ACCUM(acc[0][i][0][j], afr[i][0], b0c[j][0]);
        ACCUM(acc[0][i][0][j], afr[i][1], b0c[j][1]);
      }
    __builtin_amdgcn_s_setprio(0);
    PB();

#pragma unroll
    for (int j = 0; j < 2; j++) {
      b1r[j][0] = *(const bf16x8*)&Bh1[boffE + j * 1024 + k0e];
      b1r[j][1] = *(const bf16x8*)&Bh1[boffE + j * 1024 + k1e];
    }
    stage(0, 1, s + 1);
    PB();
    __builtin_amdgcn_s_setprio(1);
#pragma unroll
    for (int i = 0; i < 4; i++)
#pragma unroll
      for (int j = 0; j < 2; j++) {
        ACCUM(acc[0][i][1][j], afr[i][0], b1r[j][0]);
        ACCUM(acc[0][i][1][j], afr[i][1], b1r[j][1]);
      }
    __builtin_amdgcn_s_setprio(0);
    PB();

#pragma unroll
    for (int i = 0; i < 4; i++) {
      afr[i][0] = *(const bf16x8*)&Ah1[aoffE + i * 1024 + k0e];
      afr[i][1] = *(const bf16x8*)&Ah1[aoffE + i * 1024 + k1e];
    }
    stage(0, 0, s + 2);
    PB();
    __builtin_amdgcn_s_setprio(1);
#pragma unroll
    for (int i = 0; i < 4; i++)
#pragma unroll
      for (int j = 0; j < 2; j++) {
        ACCUM(acc[1][i][1][j], afr[i][0], b1r[j][0]);
        ACCUM(acc[1][i][1][j], afr[i][1], b1r[j][1]);
      }
    __builtin_amdgcn_s_setprio(0);
    if (s < NT - 2)       { asm volatile("s_waitcnt vmcnt(4)" ::: "memory"); }
    else if (s == NT - 2) { asm volatile("s_waitcnt vmcnt(2)" ::: "memory"); }
    __builtin_amdgcn_sched_barrier(0);
    __builtin_amdgcn_s_barrier();
    __builtin_amdgcn_sched_barrier(0);

    if (s < NT - 1) {
#pragma unroll
      for (int j = 0; j < 2; j++) {
        b0n[j][0] = *(const bf16x8*)&Bn0[boffE + j * 1024 + k0e];
        b0n[j][1] = *(const bf16x8*)&Bn0[boffE + j * 1024 + k1e];
      }
    }
    stage(1, 1, s + 2);
    PB();
    __builtin_amdgcn_s_setprio(1);
#pragma unroll
    for (int i = 0; i < 4; i++)
#pragma unroll
      for (int j = 0; j < 2; j++) {
        ACCUM(acc[1][i][0][j], afr[i][0], b0c[j][0]);
        ACCUM(acc[1][i][0][j], afr[i][1], b0c[j][1]);
      }
    __builtin_amdgcn_s_setprio(0);
    if (s >= NT - 2) { asm volatile("s_waitcnt vmcnt(0)" ::: "memory"); }
    else             { asm volatile("s_waitcnt vmcnt(4)" ::: "memory"); }
    __builtin_amdgcn_sched_barrier(0);
    __builtin_amdgcn_s_barrier();
    __builtin_amdgcn_sched_barrier(0);
  };

  for (int sp = 0; sp < NT; sp += 2) {
    tile(sp, b0A, b0B);
    tile(sp + 1, b0B, b0A);
  }

  // fc2 epilogue: d_out fp32 = bf2f(sb) + acc + bias
#pragma unroll
  for (int qm = 0; qm < 2; qm++)
#pragma unroll
    for (int i = 0; i < 4; i++) {
      int row = m0 + qm * 128 + wm * 64 + i * 16 + lhi * 4;
      float* out = (float*)outp;
      const u16* sbp = (const u16*)resid;
#pragma unroll
      for (int qn = 0; qn < 2; qn++)
#pragma unroll
        for (int j = 0; j < 2; j++) {
          int col = n0 + qn * 128 + wn * 32 + j * 16 + l15;
          float bv = bias[col];
#pragma unroll
          for (int rg = 0; rg < 4; rg++) {
            size_t idx = (size_t)(row + rg) * 512 + col;
            out[idx] = bf2f(sbp[idx]) + acc[qm][i][qn][j][rg] + bv;
          }
        }
    }
}

// ---------------- MFMA windowed attention (blocked bf16 qkv in, i8 out x32) -------
__global__ __launch_bounds__(256) void attn_mfma(
    const u16* __restrict__ qkv, char* __restrict__ out) {
  __shared__ __align__(16) char alds[4][15360];
  int tid = threadIdx.x;
  int wid = tid >> 6, lane = tid & 63;
  int bwin = blockIdx.x >> 2;
  int head = ((blockIdx.x & 3) << 2) + wid;
  int wi = bwin & 255;
  int wr = wi >> 4, wc = wi & 15;
  char* Wb = alds[wid];
  u16* Qr = (u16*)Wb;
  u16* Kr = (u16*)(Wb + 5120);
  u16* Vt = (u16*)(Wb + 10240);
  u16* PT = (u16*)Wb;
  int t = lane;
  int l15 = lane & 15, lhi = lane >> 4;
  size_t tok = (size_t)(bwin << 6) + t;
  const u16* qb = qkv + (size_t)head * 2097152 + tok * 32;
  union U { uint4 u; u16 s[8]; };
  U vq[4], vk[4], vv[4];
#pragma unroll
  for (int g = 0; g < 4; g++) {
    vq[g].u = *(const uint4*)(qb + (g << 3));
    vk[g].u = *(const uint4*)(qb + 33554432 + (g << 3));
    vv[g].u = *(const uint4*)(qb + 67108864 + (g << 3));
  }
  float q[32], k[32];
#pragma unroll
  for (int j = 0; j < 32; j++) {
    q[j] = bf2f(vq[j >> 3].s[j & 7]);
    k[j] = bf2f(vk[j >> 3].s[j & 7]);
  }
  int r = t >> 3, c = t & 7;
#pragma unroll
  for (int d = 0; d < 16; d++) {
    float pos = (d < 8) ? (float)r : (float)c;
    int dd = (d < 8) ? d : d - 8;
    float ang = pos * __expf(-(float)dd * 1.1512925465f);
    float sn, cs;
    __sincosf(ang, &sn, &cs);
    float q1 = q[d], q2 = q[d + 16];
    q[d] = q1 * cs - q2 * sn;  q[d + 16] = q2 * cs + q1 * sn;
    float k1 = k[d], k2 = k[d + 16];
    k[d] = k1 * cs - k2 * sn;  k[d + 16] = k2 * cs + k1 * sn;
  }
#pragma unroll
  for (int j = 0; j < 32; j++) q[j] *= 0.17677669529663687f;
#pragma unroll
  for (int sl = 0; sl < 4; sl++) {
    U tq, tk;
#pragma unroll
    for (int j = 0; j < 8; j++) { tq.s[j] = f2bf(q[sl * 8 + j]); tk.s[j] = f2bf(k[sl * 8 + j]); }
    *(uint4*)(Qr + t * 40 + sl * 8) = tq.u;
    *(uint4*)(Kr + t * 40 + sl * 8) = tk.u;
  }
#pragma unroll
  for (int j = 0; j < 32; j++) Vt[j * 72 + t] = vv[j >> 3].s[j & 7];
  bf16x8 kf[4], qf[4];
#pragma unroll
  for (int i = 0; i < 4; i++) {
    kf[i] = *(const bf16x8*)(Kr + (i * 16 + l15) * 40 + lhi * 8);
    qf[i] = *(const bf16x8*)(Qr + (i * 16 + l15) * 40 + lhi * 8);
  }
  f32x4 zz = {0.f, 0.f, 0.f, 0.f};
  f32x4 st[4][4];
#pragma unroll
  for (int mi = 0; mi < 4; mi++)
#pragma unroll
    for (int nj = 0; nj < 4; nj++)
      st[mi][nj] = __builtin_amdgcn_mfma_f32_16x16x32_bf16(kf[mi], qf[nj], zz, 0, 0, 0);
  if (wr == 15 || wc == 15) {
    int idh = (wr == 15) ? ((r >= 4) ? 2 : 1) : 0;
    int idw = (wc == 15) ? ((c >= 4) ? 2 : 1) : 0;
    int code = idh * 3 + idw;
    int cq[4], cm[4][4];
#pragma unroll
    for (int nj = 0; nj < 4; nj++) cq[nj] = __shfl(code, nj * 16 + l15);
#pragma unroll
    for (int mi = 0; mi < 4; mi++)
#pragma unroll
      for (int rg = 0; rg < 4; rg++) cm[mi][rg] = __shfl(code, mi * 16 + lhi * 4 + rg);
#pragma unroll
    for (int mi = 0; mi < 4; mi++)
#pragma unroll
      for (int nj = 0; nj < 4; nj++)
#pragma unroll
        for (int rg = 0; rg < 4; rg++)
          if (cm[mi][rg] != cq[nj]) st[mi][nj][rg] -= 100.f;
  }
  float inv_[4];
#pragma unroll
  for (int nj = 0; nj < 4; nj++) {
    float mx = -1e30f;
#pragma unroll
    for (int mi = 0; mi < 4; mi++)
#pragma unroll
      for (int rg = 0; rg < 4; rg++) mx = fmaxf(mx, st[mi][nj][rg]);
    mx = fmaxf(mx, __shfl_xor(mx, 16));
    mx = fmaxf(mx, __shfl_xor(mx, 32));
    float sum = 0.f;
#pragma unroll
    for (int mi = 0; mi < 4; mi++)
#pragma unroll
      for (int rg = 0; rg < 4; rg++) {
        float p = __expf(st[mi][nj][rg] - mx);
        st[mi][nj][rg] = p;
        sum += p;
      }
    sum += __shfl_xor(sum, 16);
    sum += __shfl_xor(sum, 32);
    inv_[nj] = 1.f / sum;
  }
#pragma unroll
  for (int mi = 0; mi < 4; mi++)
#pragma unroll
    for (int nj = 0; nj < 4; nj++) {
      uint32_t lo, hi;
      asm("v_cvt_pk_bf16_f32 %0, %1, %2" : "=v"(lo) : "v"(st[mi][nj][0]), "v"(st[mi][nj][1]));
      asm("v_cvt_pk_bf16_f32 %0, %1, %2" : "=v"(hi) : "v"(st[mi][nj][2]), "v"(st[mi][nj][3]));
      uint2 pr; pr.x = lo; pr.y = hi;
      *(uint2*)(PT + (nj * 16 + l15) * 72 + mi * 16 + lhi * 4) = pr;
    }
  bf16x8 vf[2][2], pf[4][2];
#pragma unroll
  for (int i = 0; i < 2; i++)
#pragma unroll
    for (int kc = 0; kc < 2; kc++)
      vf[i][kc] = *(const bf16x8*)(Vt + (i * 16 + l15) * 72 + kc * 32 + lhi * 8);
#pragma unroll
  for (int nj = 0; nj < 4; nj++)
#pragma unroll
    for (int kc = 0; kc < 2; kc++)
      pf[nj][kc] = *(const bf16x8*)(PT + (nj * 16 + l15) * 72 + kc * 32 + lhi * 8);
  // O^T -> wave-private LDS i8 [64 tok][40B rows] -> coalesced 8B global stores
  char* Ot = Wb;
#pragma unroll
  for (int i = 0; i < 2; i++)
#pragma unroll
    for (int nj = 0; nj < 4; nj++) {
      f32x4 o = __builtin_amdgcn_mfma_f32_16x16x32_bf16(vf[i][0], pf[nj][0], zz, 0, 0, 0);
      o = __builtin_amdgcn_mfma_f32_16x16x32_bf16(vf[i][1], pf[nj][1], o, 0, 0, 0);
      float iv32 = inv_[nj] * 32.f;
      uint32_t pk = q8x4(o[0] * iv32, o[1] * iv32, o[2] * iv32, o[3] * iv32, 1.f);
      *(uint32_t*)(Ot + (nj * 16 + l15) * 40 + i * 16 + lhi * 4) = pk;
    }
#pragma unroll
  for (int g = 0; g < 4; g++) {
    int tl = g * 16 + (lane >> 2);
    int ch_ = (lane & 3) << 3;
    uint2 v = *(const uint2*)(Ot + tl * 40 + ch_);
    *(uint2*)(out + (size_t)((bwin << 6) + tl) * 512 + (head << 5) + ch_) = v;
  }
}

// ---------------- launch ----------------
extern "C" void kernel_launch(void* const* d_in, const int* in_sizes, int n_in,
                              void* d_out, int out_size, void* d_ws, size_t ws_size,
                              hipStream_t stream) {
  (void)in_sizes; (void)n_in; (void)out_size; (void)ws_size;
  const float* x      = (const float*)d_in[0];
  const float* n1g    = (const float*)d_in[2];
  const float* n1b    = (const float*)d_in[3];
  const float* qkv_w  = (const float*)d_in[4];
  const float* qkv_b  = (const float*)d_in[5];
  const float* proj_w = (const float*)d_in[6];
  const float* proj_b = (const float*)d_in[7];
  const float* n2g    = (const float*)d_in[8];
  const float* n2b    = (const float*)d_in[9];
  const float* fc1_w  = (const float*)d_in[10];
  const float* fc1_b  = (const float*)d_in[11];
  const float* fc2_w  = (const float*)d_in[12];
  const float* fc2_b  = (const float*)d_in[13];

  const size_t MB = 1048576ULL;
  char* ws = (char*)d_ws;
  char* wb8     = ws;                         // [0,3MB): qkv|proj|fc1 i8 weights
  char* wq8     = wb8;
  char* wp8     = wb8 + 786432;
  char* wf18    = wb8 + 1048576;
  u16*  wb_fc2  = (u16*)(ws + 4 * MB);        // [4,6MB): fc2 bf16 weights
  char* xw8     = ws + 8 * MB;                // [8,40): LN1 i8 out; later attnout
  char* attn8   = xw8;
  u16*  qkvb    = (u16*)(ws + 72 * MB);       // [72,264): blocked bf16 qkv
  u16*  hb      = (u16*)(ws + 8 * MB);        // [8,264): fc1 bf16 h
  u16*  sb      = (u16*)(ws + 264 * MB);      // [264,328): bf16 residual s
  char* yb8     = ws + 328 * MB;              // [328,360): LN2 i8 out

  ln1_wconv<<<21504, 256, 0, stream>>>(x, n1g, n1b, xw8,
                                       qkv_w, proj_w, fc1_w, fc2_w, wb8, wb_fc2);
  gemm8i<0><<<1536, 512, 0, stream>>>(xw8, wq8, qkv_b, qkvb, nullptr, 6);
  attn_mfma<<<4096, 256, 0, stream>>>(qkvb, attn8);
  gemm8i<1><<<512, 512, 0, stream>>>(attn8, wp8, proj_b, sb, x, 2);
  ln2_q8<<<16384, 256, 0, stream>>>(sb, n2g, n2b, yb8);
  gemm8i<3><<<4096, 512, 0, stream>>>(yb8, wf18, fc1_b, hb, nullptr, 16);
  gemm8<2, 2048><<<512, 512, 0, stream>>>(hb, wb_fc2, fc2_b, d_out,
                                          (const float*)sb, 2);
}

// Round 12
// 572.807 us; speedup vs baseline: 1.7032x; 1.1207x over previous
//
#include <hip/hip_runtime.h>
#include <stdint.h>

typedef __attribute__((ext_vector_type(8))) short bf16x8;
typedef __attribute__((ext_vector_type(4))) float f32x4;
typedef __attribute__((ext_vector_type(4))) int i32x4;
typedef unsigned short u16;

#define GLD_LDS16(g, l) __builtin_amdgcn_global_load_lds( \
    (const __attribute__((address_space(1))) void*)(g),   \
    (__attribute__((address_space(3))) void*)(l), 16, 0, 0)

#define PB() do { __builtin_amdgcn_sched_barrier(0); \
                  __builtin_amdgcn_s_barrier();      \
                  __builtin_amdgcn_sched_barrier(0); } while (0)

#define ACCUM(d, a_, b_) d = __builtin_amdgcn_mfma_f32_16x16x32_bf16(a_, b_, d, 0, 0, 0)
#define ACCI(d, a_, b_)  d = __builtin_amdgcn_mfma_i32_16x16x64_i8(a_, b_, d, 0, 0, 0)

#define INV_A (1.0f / 16384.0f)   // act x16,  w x1024
#define INV_P (1.0f / 32768.0f)   // attn x32, w x1024
#define INV_H (1.0f / 65536.0f)   // h x64,    w x1024

__device__ __forceinline__ u16 f2bf(float f) {
  union { float f; uint32_t u; } a; a.f = f;
  uint32_t u = a.u;
  return (u16)((u + 0x7fffu + ((u >> 16) & 1u)) >> 16);
}
__device__ __forceinline__ float bf2f(u16 h) {
  union { uint32_t u; float f; } a; a.u = ((uint32_t)h) << 16;
  return a.f;
}
__device__ __forceinline__ uint32_t q8x4(float a, float b, float c, float d, float s) {
  int qa = (int)rintf(fminf(fmaxf(a * s, -127.f), 127.f));
  int qb = (int)rintf(fminf(fmaxf(b * s, -127.f), 127.f));
  int qc = (int)rintf(fminf(fmaxf(c * s, -127.f), 127.f));
  int qd = (int)rintf(fminf(fmaxf(d * s, -127.f), 127.f));
  return (qa & 255) | ((qb & 255) << 8) | ((qc & 255) << 16) | ((qd & 255) << 24);
}
__device__ __forceinline__ char q8(float v, float s) {
  return (char)(int)rintf(fminf(fmaxf(v * s, -127.f), 127.f));
}

// ---------------- LN1 (shift+window gather, i8 out) + all-weight i8 conversion ----
__global__ __launch_bounds__(256) void ln1_wconv(const float* __restrict__ x,
    const float* __restrict__ gw, const float* __restrict__ bw, char* __restrict__ out,
    const float* __restrict__ qw, const float* __restrict__ pw,
    const float* __restrict__ f1w, const float* __restrict__ f2w,
    char* __restrict__ wb8) {
  int bx = blockIdx.x;
  if (bx >= 16384) {
    // i8 weights: qkv | proj | fc1 | fc2, x1024, 4 per thread (4 MB total)
    int i4 = (bx - 16384) * 1024 + threadIdx.x * 4;
    float w[4];
#pragma unroll
    for (int j = 0; j < 4; j++) {
      int idx = i4 + j;
      if (idx < 786432)        w[j] = qw[idx];
      else if (idx < 1048576)  w[j] = pw[idx - 786432];
      else if (idx < 3145728)  w[j] = f1w[idx - 1048576];
      else                     w[j] = f2w[idx - 3145728];
    }
    *(uint32_t*)(wb8 + i4) = q8x4(w[0], w[1], w[2], w[3], 1024.f);
    return;
  }
  int wid = threadIdx.x >> 6;
  int lane = threadIdx.x & 63;
  int m = (bx << 2) + wid;
  int n = m & 63;
  int bwin = m >> 6;
  int b = bwin >> 8;
  int wi = bwin & 255;
  int h = (((wi >> 4) << 3) + (n >> 3) + 4) & 127;
  int w = (((wi & 15) << 3) + (n & 7) + 4) & 127;
  const float* src = x + (((size_t)((b << 7) + h) << 7) + (size_t)w) * 512;
  int ch = lane << 3;
  float4 v0 = *(const float4*)(src + ch);
  float4 v1 = *(const float4*)(src + ch + 4);
  float vv[8] = {v0.x, v0.y, v0.z, v0.w, v1.x, v1.y, v1.z, v1.w};
  float s = 0.f, s2 = 0.f;
#pragma unroll
  for (int j = 0; j < 8; j++) { s += vv[j]; s2 += vv[j] * vv[j]; }
#pragma unroll
  for (int off = 32; off; off >>= 1) {
    s += __shfl_xor(s, off);
    s2 += __shfl_xor(s2, off);
  }
  float mean = s * (1.f / 512.f);
  float var = s2 * (1.f / 512.f) - mean * mean;
  float rstd = rsqrtf(var + 1e-5f);
  float y[8];
#pragma unroll
  for (int j = 0; j < 8; j++) y[j] = (vv[j] - mean) * rstd * gw[ch + j] + bw[ch + j];
  uint2 o;
  o.x = q8x4(y[0], y[1], y[2], y[3], 16.f);
  o.y = q8x4(y[4], y[5], y[6], y[7], 16.f);
  *(uint2*)(out + ((size_t)m << 9) + ch) = o;
}

// ---------------- LN2: bf16 residual in -> i8 out ----------------
__global__ __launch_bounds__(256) void ln2_q8(const u16* __restrict__ sb,
    const float* __restrict__ gw, const float* __restrict__ bw,
    char* __restrict__ out) {
  int wid = threadIdx.x >> 6;
  int lane = threadIdx.x & 63;
  int m = (blockIdx.x << 2) + wid;
  int ch = lane << 3;
  union { uint4 u; u16 hh[8]; } in;
  in.u = *(const uint4*)(sb + ((size_t)m << 9) + ch);
  float vv[8];
#pragma unroll
  for (int j = 0; j < 8; j++) vv[j] = bf2f(in.hh[j]);
  float s = 0.f, s2 = 0.f;
#pragma unroll
  for (int j = 0; j < 8; j++) { s += vv[j]; s2 += vv[j] * vv[j]; }
#pragma unroll
  for (int off = 32; off; off >>= 1) {
    s += __shfl_xor(s, off);
    s2 += __shfl_xor(s2, off);
  }
  float mean = s * (1.f / 512.f);
  float var = s2 * (1.f / 512.f) - mean * mean;
  float rstd = rsqrtf(var + 1e-5f);
  float y[8];
#pragma unroll
  for (int j = 0; j < 8; j++) y[j] = (vv[j] - mean) * rstd * gw[ch + j] + bw[ch + j];
  uint2 o;
  o.x = q8x4(y[0], y[1], y[2], y[3], 16.f);
  o.y = q8x4(y[4], y[5], y[6], y[7], 16.f);
  *(uint2*)(out + ((size_t)m << 9) + ch) = o;
}

// ---------------- i8 256x256-tile GEMM (NT = K/128, K-tile = 128 i8) --------------
// R10 phase engine; mfma_i32_16x16x64_i8; i32 acc; dequant in epilogue.
// EPI 0: qkv -> bf16 BLOCKED [selhead][token][32] (+bias), INV_A
// EPI 1: proj -> bf16 s = x + acc*INV_P + bias (window-reverse scatter)
// EPI 2: fc2 -> d_out fp32 = bf2f(sb) + acc*INV_H + bias, ld=2048
// EPI 3: fc1 -> SwiGLU fused, i8 h out (x64), ld=2048
template<int EPI, int K>
__global__ __launch_bounds__(512, 1) void gemm8i(
    const char* __restrict__ A, const char* __restrict__ Bw,
    const float* __restrict__ bias, void* __restrict__ outp,
    const float* __restrict__ resid, int NTN) {
  __shared__ __align__(16) char lds[2][4][16384];  // [buf][A0,A1,B0,B1][128r x 128B]
  const int NT = K / 128;
  int bid = blockIdx.x;
  int nwg = gridDim.x;
  int wg = (bid & 7) * (nwg >> 3) + (bid >> 3);
  int mt = wg / NTN, nt = wg - mt * NTN;
  int m0 = mt << 8;
  int n0 = (EPI == 3) ? (nt << 7) : (nt << 8);

  int tid = threadIdx.x;
  int wid = tid >> 6, lane = tid & 63;
  int wm = wid >> 2, wn = wid & 3;
  int l15 = lane & 15, lhi = lane >> 4;
  int swz = (lane & 7) << 4;

  int sr0 = tid >> 3;                               // 0..63
  int xk = (((tid & 7) ^ ((tid >> 3) & 7)) << 4);   // pre-swizzled source byte offset

  auto stage = [&](int mat, int hh, int t) {
    if (t >= NT) return;
    char* ld = &lds[t & 1][mat * 2 + hh][0] + (wid << 10);
    const char* g0;
    if (mat == 0) {
      g0 = A + (size_t)(m0 + hh * 128 + sr0) * K + t * 128 + xk;
    } else {
      int rb;
      if (EPI == 3) rb = (hh ? 2048 : 0) + n0 + sr0;
      else          rb = n0 + hh * 128 + sr0;
      g0 = Bw + (size_t)rb * K + t * 128 + xk;
    }
    GLD_LDS16(g0, ld);
    GLD_LDS16(g0 + (size_t)64 * K, ld + 8192);
  };

  i32x4 acc[2][4][2][2] = {};
  i32x4 afr[4][2], b1r[2][2];
  i32x4 b0A[2][2], b0B[2][2];

  int aoffB = (wm * 64 + l15) * 128;
  int boffB = (wn * 32 + l15) * 128;
  int k0b = (lhi * 16) ^ swz;
  int k1b = (64 + lhi * 16) ^ swz;

  stage(0, 0, 0); stage(1, 1, 0); stage(1, 0, 0); stage(0, 1, 0);
  stage(0, 0, 1); stage(1, 1, 1);
  asm volatile("s_waitcnt vmcnt(4)" ::: "memory");
  __builtin_amdgcn_sched_barrier(0);
  __builtin_amdgcn_s_barrier();
  __builtin_amdgcn_sched_barrier(0);
  {
    const char* B00 = &lds[0][2][0];
#pragma unroll
    for (int j = 0; j < 2; j++) {
      b0A[j][0] = *(const i32x4*)&B00[boffB + j * 2048 + k0b];
      b0A[j][1] = *(const i32x4*)&B00[boffB + j * 2048 + k1b];
    }
  }

  auto tile = [&](int s, i32x4 (&b0c)[2][2], i32x4 (&b0n)[2][2]) {
    const char* Ah0 = &lds[s & 1][0][0];
    const char* Ah1 = &lds[s & 1][1][0];
    const char* Bh1 = &lds[s & 1][3][0];
    const char* Bn0 = &lds[(s + 1) & 1][2][0];

    // ---- P0: read A0 (8); stage B0(s+1); MFMA (A0 x B0cur)
#pragma unroll
    for (int i = 0; i < 4; i++) {
      afr[i][0] = *(const i32x4*)&Ah0[aoffB + i * 2048 + k0b];
      afr[i][1] = *(const i32x4*)&Ah0[aoffB + i * 2048 + k1b];
    }
    stage(1, 0, s + 1);
    PB();
    __builtin_amdgcn_s_setprio(1);
#pragma unroll
    for (int i = 0; i < 4; i++)
#pragma unroll
      for (int j = 0; j < 2; j++) {
        ACCI(acc[0][i][0][j], afr[i][0], b0c[j][0]);
        ACCI(acc[0][i][0][j], afr[i][1], b0c[j][1]);
      }
    __builtin_amdgcn_s_setprio(0);
    PB();

    // ---- P1: read B1 (4); stage A1(s+1); MFMA (A0 x B1)
#pragma unroll
    for (int j = 0; j < 2; j++) {
      b1r[j][0] = *(const i32x4*)&Bh1[boffB + j * 2048 + k0b];
      b1r[j][1] = *(const i32x4*)&Bh1[boffB + j * 2048 + k1b];
    }
    stage(0, 1, s + 1);
    PB();
    __builtin_amdgcn_s_setprio(1);
#pragma unroll
    for (int i = 0; i < 4; i++)
#pragma unroll
      for (int j = 0; j < 2; j++) {
        ACCI(acc[0][i][1][j], afr[i][0], b1r[j][0]);
        ACCI(acc[0][i][1][j], afr[i][1], b1r[j][1]);
      }
    __builtin_amdgcn_s_setprio(0);
    PB();

    // ---- P2: read A1 (8); stage A0(s+2); MFMA (A1 x B1); gate B0(s+1)
#pragma unroll
    for (int i = 0; i < 4; i++) {
      afr[i][0] = *(const i32x4*)&Ah1[aoffB + i * 2048 + k0b];
      afr[i][1] = *(const i32x4*)&Ah1[aoffB + i * 2048 + k1b];
    }
    stage(0, 0, s + 2);
    PB();
    __builtin_amdgcn_s_setprio(1);
#pragma unroll
    for (int i = 0; i < 4; i++)
#pragma unroll
      for (int j = 0; j < 2; j++) {
        ACCI(acc[1][i][1][j], afr[i][0], b1r[j][0]);
        ACCI(acc[1][i][1][j], afr[i][1], b1r[j][1]);
      }
    __builtin_amdgcn_s_setprio(0);
    if (s < NT - 2)       { asm volatile("s_waitcnt vmcnt(4)" ::: "memory"); }
    else if (s == NT - 2) { asm volatile("s_waitcnt vmcnt(2)" ::: "memory"); }
    __builtin_amdgcn_sched_barrier(0);
    __builtin_amdgcn_s_barrier();
    __builtin_amdgcn_sched_barrier(0);

    // ---- P3: read B0(s+1) (4, cross-buffer); stage B1(s+2); MFMA (A1 x B0cur)
    if (s < NT - 1) {
#pragma unroll
      for (int j = 0; j < 2; j++) {
        b0n[j][0] = *(const i32x4*)&Bn0[boffB + j * 2048 + k0b];
        b0n[j][1] = *(const i32x4*)&Bn0[boffB + j * 2048 + k1b];
      }
    }
    stage(1, 1, s + 2);
    PB();
    __builtin_amdgcn_s_setprio(1);
#pragma unroll
    for (int i = 0; i < 4; i++)
#pragma unroll
      for (int j = 0; j < 2; j++) {
        ACCI(acc[1][i][0][j], afr[i][0], b0c[j][0]);
        ACCI(acc[1][i][0][j], afr[i][1], b0c[j][1]);
      }
    __builtin_amdgcn_s_setprio(0);
    if (s >= NT - 2) { asm volatile("s_waitcnt vmcnt(0)" ::: "memory"); }
    else             { asm volatile("s_waitcnt vmcnt(4)" ::: "memory"); }
    __builtin_amdgcn_sched_barrier(0);
    __builtin_amdgcn_s_barrier();
    __builtin_amdgcn_sched_barrier(0);
  };

  for (int sp = 0; sp < NT; sp += 2) {
    tile(sp, b0A, b0B);
    tile(sp + 1, b0B, b0A);
  }

  // ---------------- epilogue (dequant) ----------------
#pragma unroll
  for (int qm = 0; qm < 2; qm++)
#pragma unroll
    for (int i = 0; i < 4; i++) {
      int row = m0 + qm * 128 + wm * 64 + i * 16 + lhi * 4;
      if (EPI == 0) {
        u16* out = (u16*)outp;
#pragma unroll
        for (int qn = 0; qn < 2; qn++)
#pragma unroll
          for (int j = 0; j < 2; j++) {
            int colb = n0 + qn * 128 + wn * 32 + j * 16;
            int col = colb + l15;
            int sh = colb >> 5;
            int d = (colb & 31) + l15;
            float bv = bias[col];
#pragma unroll
            for (int rg = 0; rg < 4; rg++)
              out[(size_t)sh * 2097152 + (size_t)(row + rg) * 32 + d] =
                  f2bf((float)acc[qm][i][qn][j][rg] * INV_A + bv);
          }
      } else if (EPI == 1) {
        u16* sbw = (u16*)outp;
#pragma unroll
        for (int rg = 0; rg < 4; rg++) {
          int m = row + rg;
          int b = m >> 14, wi2 = (m >> 6) & 255, n = m & 63;
          int h = (((wi2 >> 4) << 3) + (n >> 3) + 4) & 127;
          int w = (((wi2 & 15) << 3) + (n & 7) + 4) & 127;
          size_t pix = (((size_t)((b << 7) + h) << 7) + (size_t)w) << 9;
#pragma unroll
          for (int qn = 0; qn < 2; qn++)
#pragma unroll
            for (int j = 0; j < 2; j++) {
              int col = n0 + qn * 128 + wn * 32 + j * 16 + l15;
              sbw[pix + col] = f2bf(resid[pix + col] +
                                    (float)acc[qm][i][qn][j][rg] * INV_P + bias[col]);
            }
        }
      } else if (EPI == 2) {
        float* out = (float*)outp;
        const u16* sbp = (const u16*)resid;
#pragma unroll
        for (int qn = 0; qn < 2; qn++)
#pragma unroll
          for (int j = 0; j < 2; j++) {
            int col = n0 + qn * 128 + wn * 32 + j * 16 + l15;
            float bv = bias[col];
#pragma unroll
            for (int rg = 0; rg < 4; rg++) {
              size_t idx = (size_t)(row + rg) * 512 + col;
              out[idx] = bf2f(sbp[idx]) + (float)acc[qm][i][qn][j][rg] * INV_H + bv;
            }
          }
      } else {
        char* out = (char*)outp;
#pragma unroll
        for (int j = 0; j < 2; j++) {
          int col = n0 + wn * 32 + j * 16 + l15;
          float ba_ = bias[col], bg_ = bias[col + 2048];
#pragma unroll
          for (int rg = 0; rg < 4; rg++) {
            float av = (float)acc[qm][i][0][j][rg] * INV_A + ba_;
            float gv = (float)acc[qm][i][1][j][rg] * INV_A + bg_;
            float sw = gv / (1.f + __expf(-gv));
            out[(size_t)(row + rg) * 2048 + col] = q8(sw * av, 64.f);
          }
        }
      }
    }
}

// ---------------- MFMA windowed attention (blocked bf16 qkv in, i8 out x32) -------
__global__ __launch_bounds__(256) void attn_mfma(
    const u16* __restrict__ qkv, char* __restrict__ out) {
  __shared__ __align__(16) char alds[4][15360];
  int tid = threadIdx.x;
  int wid = tid >> 6, lane = tid & 63;
  int bwin = blockIdx.x >> 2;
  int head = ((blockIdx.x & 3) << 2) + wid;
  int wi = bwin & 255;
  int wr = wi >> 4, wc = wi & 15;
  char* Wb = alds[wid];
  u16* Qr = (u16*)Wb;
  u16* Kr = (u16*)(Wb + 5120);
  u16* Vt = (u16*)(Wb + 10240);
  u16* PT = (u16*)Wb;
  int t = lane;
  int l15 = lane & 15, lhi = lane >> 4;
  size_t tok = (size_t)(bwin << 6) + t;
  const u16* qb = qkv + (size_t)head * 2097152 + tok * 32;
  union U { uint4 u; u16 s[8]; };
  U vq[4], vk[4], vv[4];
#pragma unroll
  for (int g = 0; g < 4; g++) {
    vq[g].u = *(const uint4*)(qb + (g << 3));
    vk[g].u = *(const uint4*)(qb + 33554432 + (g << 3));
    vv[g].u = *(const uint4*)(qb + 67108864 + (g << 3));
  }
  float q[32], k[32];
#pragma unroll
  for (int j = 0; j < 32; j++) {
    q[j] = bf2f(vq[j >> 3].s[j & 7]);
    k[j] = bf2f(vk[j >> 3].s[j & 7]);
  }
  int r = t >> 3, c = t & 7;
#pragma unroll
  for (int d = 0; d < 16; d++) {
    float pos = (d < 8) ? (float)r : (float)c;
    int dd = (d < 8) ? d : d - 8;
    float ang = pos * __expf(-(float)dd * 1.1512925465f);
    float sn, cs;
    __sincosf(ang, &sn, &cs);
    float q1 = q[d], q2 = q[d + 16];
    q[d] = q1 * cs - q2 * sn;  q[d + 16] = q2 * cs + q1 * sn;
    float k1 = k[d], k2 = k[d + 16];
    k[d] = k1 * cs - k2 * sn;  k[d + 16] = k2 * cs + k1 * sn;
  }
#pragma unroll
  for (int j = 0; j < 32; j++) q[j] *= 0.17677669529663687f;
#pragma unroll
  for (int sl = 0; sl < 4; sl++) {
    U tq, tk;
#pragma unroll
    for (int j = 0; j < 8; j++) { tq.s[j] = f2bf(q[sl * 8 + j]); tk.s[j] = f2bf(k[sl * 8 + j]); }
    *(uint4*)(Qr + t * 40 + sl * 8) = tq.u;
    *(uint4*)(Kr + t * 40 + sl * 8) = tk.u;
  }
#pragma unroll
  for (int j = 0; j < 32; j++) Vt[j * 72 + t] = vv[j >> 3].s[j & 7];
  bf16x8 kf[4], qf[4];
#pragma unroll
  for (int i = 0; i < 4; i++) {
    kf[i] = *(const bf16x8*)(Kr + (i * 16 + l15) * 40 + lhi * 8);
    qf[i] = *(const bf16x8*)(Qr + (i * 16 + l15) * 40 + lhi * 8);
  }
  f32x4 zz = {0.f, 0.f, 0.f, 0.f};
  f32x4 st[4][4];
#pragma unroll
  for (int mi = 0; mi < 4; mi++)
#pragma unroll
    for (int nj = 0; nj < 4; nj++)
      st[mi][nj] = __builtin_amdgcn_mfma_f32_16x16x32_bf16(kf[mi], qf[nj], zz, 0, 0, 0);
  if (wr == 15 || wc == 15) {
    int idh = (wr == 15) ? ((r >= 4) ? 2 : 1) : 0;
    int idw = (wc == 15) ? ((c >= 4) ? 2 : 1) : 0;
    int code = idh * 3 + idw;
    int cq[4], cm[4][4];
#pragma unroll
    for (int nj = 0; nj < 4; nj++) cq[nj] = __shfl(code, nj * 16 + l15);
#pragma unroll
    for (int mi = 0; mi < 4; mi++)
#pragma unroll
      for (int rg = 0; rg < 4; rg++) cm[mi][rg] = __shfl(code, mi * 16 + lhi * 4 + rg);
#pragma unroll
    for (int mi = 0; mi < 4; mi++)
#pragma unroll
      for (int nj = 0; nj < 4; nj++)
#pragma unroll
        for (int rg = 0; rg < 4; rg++)
          if (cm[mi][rg] != cq[nj]) st[mi][nj][rg] -= 100.f;
  }
  float inv_[4];
#pragma unroll
  for (int nj = 0; nj < 4; nj++) {
    float mx = -1e30f;
#pragma unroll
    for (int mi = 0; mi < 4; mi++)
#pragma unroll
      for (int rg = 0; rg < 4; rg++) mx = fmaxf(mx, st[mi][nj][rg]);
    mx = fmaxf(mx, __shfl_xor(mx, 16));
    mx = fmaxf(mx, __shfl_xor(mx, 32));
    float sum = 0.f;
#pragma unroll
    for (int mi = 0; mi < 4; mi++)
#pragma unroll
      for (int rg = 0; rg < 4; rg++) {
        float p = __expf(st[mi][nj][rg] - mx);
        st[mi][nj][rg] = p;
        sum += p;
      }
    sum += __shfl_xor(sum, 16);
    sum += __shfl_xor(sum, 32);
    inv_[nj] = 1.f / sum;
  }
#pragma unroll
  for (int mi = 0; mi < 4; mi++)
#pragma unroll
    for (int nj = 0; nj < 4; nj++) {
      uint32_t lo, hi;
      asm("v_cvt_pk_bf16_f32 %0, %1, %2" : "=v"(lo) : "v"(st[mi][nj][0]), "v"(st[mi][nj][1]));
      asm("v_cvt_pk_bf16_f32 %0, %1, %2" : "=v"(hi) : "v"(st[mi][nj][2]), "v"(st[mi][nj][3]));
      uint2 pr; pr.x = lo; pr.y = hi;
      *(uint2*)(PT + (nj * 16 + l15) * 72 + mi * 16 + lhi * 4) = pr;
    }
  bf16x8 vf[2][2], pf[4][2];
#pragma unroll
  for (int i = 0; i < 2; i++)
#pragma unroll
    for (int kc = 0; kc < 2; kc++)
      vf[i][kc] = *(const bf16x8*)(Vt + (i * 16 + l15) * 72 + kc * 32 + lhi * 8);
#pragma unroll
  for (int nj = 0; nj < 4; nj++)
#pragma unroll
    for (int kc = 0; kc < 2; kc++)
      pf[nj][kc] = *(const bf16x8*)(PT + (nj * 16 + l15) * 72 + kc * 32 + lhi * 8);
  char* Ot = Wb;
#pragma unroll
  for (int i = 0; i < 2; i++)
#pragma unroll
    for (int nj = 0; nj < 4; nj++) {
      f32x4 o = __builtin_amdgcn_mfma_f32_16x16x32_bf16(vf[i][0], pf[nj][0], zz, 0, 0, 0);
      o = __builtin_amdgcn_mfma_f32_16x16x32_bf16(vf[i][1], pf[nj][1], o, 0, 0, 0);
      float iv32 = inv_[nj] * 32.f;
      uint32_t pk = q8x4(o[0] * iv32, o[1] * iv32, o[2] * iv32, o[3] * iv32, 1.f);
      *(uint32_t*)(Ot + (nj * 16 + l15) * 40 + i * 16 + lhi * 4) = pk;
    }
#pragma unroll
  for (int g = 0; g < 4; g++) {
    int tl = g * 16 + (lane >> 2);
    int ch_ = (lane & 3) << 3;
    uint2 v = *(const uint2*)(Ot + tl * 40 + ch_);
    *(uint2*)(out + (size_t)((bwin << 6) + tl) * 512 + (head << 5) + ch_) = v;
  }
}

// ---------------- launch ----------------
extern "C" void kernel_launch(void* const* d_in, const int* in_sizes, int n_in,
                              void* d_out, int out_size, void* d_ws, size_t ws_size,
                              hipStream_t stream) {
  (void)in_sizes; (void)n_in; (void)out_size; (void)ws_size;
  const float* x      = (const float*)d_in[0];
  const float* n1g    = (const float*)d_in[2];
  const float* n1b    = (const float*)d_in[3];
  const float* qkv_w  = (const float*)d_in[4];
  const float* qkv_b  = (const float*)d_in[5];
  const float* proj_w = (const float*)d_in[6];
  const float* proj_b = (const float*)d_in[7];
  const float* n2g    = (const float*)d_in[8];
  const float* n2b    = (const float*)d_in[9];
  const float* fc1_w  = (const float*)d_in[10];
  const float* fc1_b  = (const float*)d_in[11];
  const float* fc2_w  = (const float*)d_in[12];
  const float* fc2_b  = (const float*)d_in[13];

  const size_t MB = 1048576ULL;
  char* ws = (char*)d_ws;
  char* wb8  = ws;                        // [0,4MB): qkv|proj|fc1|fc2 i8 weights
  char* wq8  = wb8;
  char* wp8  = wb8 + 786432;
  char* wf18 = wb8 + 1048576;
  char* wf28 = wb8 + 3145728;
  char* xw8  = ws + 8 * MB;               // [8,40): LN1 i8; later attn8
  char* attn8 = xw8;
  u16*  qkvb = (u16*)(ws + 72 * MB);      // [72,264): blocked bf16 qkv
  char* hb8  = ws + 8 * MB;               // [8,136): fc1 i8 h (qkv/attn dead)
  u16*  sb   = (u16*)(ws + 264 * MB);     // [264,328): bf16 residual s
  char* yb8  = ws + 328 * MB;             // [328,360): LN2 i8 out

  ln1_wconv<<<20480, 256, 0, stream>>>(x, n1g, n1b, xw8,
                                       qkv_w, proj_w, fc1_w, fc2_w, wb8);
  gemm8i<0, 512><<<1536, 512, 0, stream>>>(xw8, wq8, qkv_b, qkvb, nullptr, 6);
  attn_mfma<<<4096, 256, 0, stream>>>(qkvb, attn8);
  gemm8i<1, 512><<<512, 512, 0, stream>>>(attn8, wp8, proj_b, sb, x, 2);
  ln2_q8<<<16384, 256, 0, stream>>>(sb, n2g, n2b, yb8);
  gemm8i<3, 512><<<4096, 512, 0, stream>>>(yb8, wf18, fc1_b, hb8, nullptr, 16);
  gemm8i<2, 2048><<<512, 512, 0, stream>>>(hb8, wf28, fc2_b, d_out,
                                           (const float*)sb, 2);
}

// Round 13
// 565.438 us; speedup vs baseline: 1.7254x; 1.0130x over previous
//
#include <hip/hip_runtime.h>
#include <stdint.h>

typedef __attribute__((ext_vector_type(8))) short bf16x8;
typedef __attribute__((ext_vector_type(4))) float f32x4;
typedef __attribute__((ext_vector_type(4))) int i32x4;
typedef unsigned short u16;

#define GLD_LDS16(g, l) __builtin_amdgcn_global_load_lds( \
    (const __attribute__((address_space(1))) void*)(g),   \
    (__attribute__((address_space(3))) void*)(l), 16, 0, 0)

#define PB() do { __builtin_amdgcn_sched_barrier(0); \
                  __builtin_amdgcn_s_barrier();      \
                  __builtin_amdgcn_sched_barrier(0); } while (0)

#define ACCI(d, a_, b_)  d = __builtin_amdgcn_mfma_i32_16x16x64_i8(a_, b_, d, 0, 0, 0)

#define INV_A (1.0f / 16384.0f)   // act x16,  w x1024
#define INV_P (1.0f / 32768.0f)   // attn x32, w x1024
#define INV_H (1.0f / 65536.0f)   // h x64,    w x1024

__device__ __forceinline__ u16 f2bf(float f) {
  union { float f; uint32_t u; } a; a.f = f;
  uint32_t u = a.u;
  return (u16)((u + 0x7fffu + ((u >> 16) & 1u)) >> 16);
}
__device__ __forceinline__ float bf2f(u16 h) {
  union { uint32_t u; float f; } a; a.u = ((uint32_t)h) << 16;
  return a.f;
}
__device__ __forceinline__ uint32_t q8x4(float a, float b, float c, float d, float s) {
  int qa = (int)rintf(fminf(fmaxf(a * s, -127.f), 127.f));
  int qb = (int)rintf(fminf(fmaxf(b * s, -127.f), 127.f));
  int qc = (int)rintf(fminf(fmaxf(c * s, -127.f), 127.f));
  int qd = (int)rintf(fminf(fmaxf(d * s, -127.f), 127.f));
  return (qa & 255) | ((qb & 255) << 8) | ((qc & 255) << 16) | ((qd & 255) << 24);
}
__device__ __forceinline__ char q8(float v, float s) {
  return (char)(int)rintf(fminf(fmaxf(v * s, -127.f), 127.f));
}

// ---------------- LN1 (shift+window gather, i8 out) + all-weight i8 conversion ----
__global__ __launch_bounds__(256) void ln1_wconv(const float* __restrict__ x,
    const float* __restrict__ gw, const float* __restrict__ bw, char* __restrict__ out,
    const float* __restrict__ qw, const float* __restrict__ pw,
    const float* __restrict__ f1w, const float* __restrict__ f2w,
    char* __restrict__ wb8) {
  int bx = blockIdx.x;
  if (bx >= 16384) {
    int i4 = (bx - 16384) * 1024 + threadIdx.x * 4;
    float w[4];
#pragma unroll
    for (int j = 0; j < 4; j++) {
      int idx = i4 + j;
      if (idx < 786432)        w[j] = qw[idx];
      else if (idx < 1048576)  w[j] = pw[idx - 786432];
      else if (idx < 3145728)  w[j] = f1w[idx - 1048576];
      else                     w[j] = f2w[idx - 3145728];
    }
    *(uint32_t*)(wb8 + i4) = q8x4(w[0], w[1], w[2], w[3], 1024.f);
    return;
  }
  int wid = threadIdx.x >> 6;
  int lane = threadIdx.x & 63;
  int m = (bx << 2) + wid;
  int n = m & 63;
  int bwin = m >> 6;
  int b = bwin >> 8;
  int wi = bwin & 255;
  int h = (((wi >> 4) << 3) + (n >> 3) + 4) & 127;
  int w = (((wi & 15) << 3) + (n & 7) + 4) & 127;
  const float* src = x + (((size_t)((b << 7) + h) << 7) + (size_t)w) * 512;
  int ch = lane << 3;
  float4 v0 = *(const float4*)(src + ch);
  float4 v1 = *(const float4*)(src + ch + 4);
  float vv[8] = {v0.x, v0.y, v0.z, v0.w, v1.x, v1.y, v1.z, v1.w};
  float s = 0.f, s2 = 0.f;
#pragma unroll
  for (int j = 0; j < 8; j++) { s += vv[j]; s2 += vv[j] * vv[j]; }
#pragma unroll
  for (int off = 32; off; off >>= 1) {
    s += __shfl_xor(s, off);
    s2 += __shfl_xor(s2, off);
  }
  float mean = s * (1.f / 512.f);
  float var = s2 * (1.f / 512.f) - mean * mean;
  float rstd = rsqrtf(var + 1e-5f);
  float y[8];
#pragma unroll
  for (int j = 0; j < 8; j++) y[j] = (vv[j] - mean) * rstd * gw[ch + j] + bw[ch + j];
  uint2 o;
  o.x = q8x4(y[0], y[1], y[2], y[3], 16.f);
  o.y = q8x4(y[4], y[5], y[6], y[7], 16.f);
  *(uint2*)(out + ((size_t)m << 9) + ch) = o;
}

// ---------------- LN2: bf16 residual in -> i8 out ----------------
__global__ __launch_bounds__(256) void ln2_q8(const u16* __restrict__ sb,
    const float* __restrict__ gw, const float* __restrict__ bw,
    char* __restrict__ out) {
  int wid = threadIdx.x >> 6;
  int lane = threadIdx.x & 63;
  int m = (blockIdx.x << 2) + wid;
  int ch = lane << 3;
  union { uint4 u; u16 hh[8]; } in;
  in.u = *(const uint4*)(sb + ((size_t)m << 9) + ch);
  float vv[8];
#pragma unroll
  for (int j = 0; j < 8; j++) vv[j] = bf2f(in.hh[j]);
  float s = 0.f, s2 = 0.f;
#pragma unroll
  for (int j = 0; j < 8; j++) { s += vv[j]; s2 += vv[j] * vv[j]; }
#pragma unroll
  for (int off = 32; off; off >>= 1) {
    s += __shfl_xor(s, off);
    s2 += __shfl_xor(s2, off);
  }
  float mean = s * (1.f / 512.f);
  float var = s2 * (1.f / 512.f) - mean * mean;
  float rstd = rsqrtf(var + 1e-5f);
  float y[8];
#pragma unroll
  for (int j = 0; j < 8; j++) y[j] = (vv[j] - mean) * rstd * gw[ch + j] + bw[ch + j];
  uint2 o;
  o.x = q8x4(y[0], y[1], y[2], y[3], 16.f);
  o.y = q8x4(y[4], y[5], y[6], y[7], 16.f);
  *(uint2*)(out + ((size_t)m << 9) + ch) = o;
}

// ---------------- i8 128x256-tile GEMM, 2 blocks/CU, K-tile=64B ------------------
// 8 waves = wm(2: 64 rows) x wn(4: 32 cols per B-half). Per wave: 64x32x2 halves.
// LDS: [buf2][A,B0,B1][128 rows x 64B] = 48KB. Chunk swizzle c ^= (row>>1)&3.
// Pipeline: P0{read A+B0; stage B1(s+1); PB; 8 MFMA; PB}
//           P1{read B1; stage A,B0(s+2); PB; 8 MFMA; gate vmcnt(2|0); barrier}
// EPI 0: qkv -> bf16 BLOCKED [selhead][token][32] (+bias), INV_A, out-cols 256
// EPI 1: proj -> bf16 s = x + acc*INV_P + bias (window-reverse scatter), 256
// EPI 2: fc2 -> d_out fp32 = bf2f(sb) + acc*INV_H + bias, ld=512, 256
// EPI 3: fc1 -> SwiGLU (B0=a rows n0.., B1=gate rows 2048+n0..), i8 out x64, 128
template<int EPI, int K>
__global__ __launch_bounds__(512, 4) void gemm2i(
    const char* __restrict__ A, const char* __restrict__ Bw,
    const float* __restrict__ bias, void* __restrict__ outp,
    const float* __restrict__ resid, int NTN) {
  __shared__ __align__(16) char lds[2][3][8192];
  const int NT = K / 64;
  int bid = blockIdx.x;
  int nwg = gridDim.x;
  int wg = (bid & 7) * (nwg >> 3) + (bid >> 3);   // bijective XCD swizzle (nwg%8==0)
  int mt = wg / NTN, nt = wg - mt * NTN;
  int m0 = mt << 7;
  int n0 = (EPI == 3) ? (nt << 7) : (nt << 8);

  int tid = threadIdx.x;
  int wid = tid >> 6, lane = tid & 63;
  int wm = wid >> 2, wn = wid & 3;
  int l15 = lane & 15, lhi = lane >> 4;

  int sr0 = tid >> 2;                          // staging row 0..127
  int sc = (tid & 3) ^ ((sr0 >> 1) & 3);       // swizzled source chunk
  const char* gA  = A  + (size_t)(m0 + sr0) * K + sc * 16;
  const char* gB0 = Bw + (size_t)(n0 + sr0) * K + sc * 16;
  const char* gB1 = (EPI == 3)
      ? (Bw + (size_t)(2048 + n0 + sr0) * K + sc * 16)
      : (Bw + (size_t)(n0 + 128 + sr0) * K + sc * 16);

  auto stage = [&](int slot, const char* gp, int t) {
    if (t >= NT) return;
    char* ld = &lds[t & 1][slot][0] + tid * 16;
    GLD_LDS16(gp + t * 64, ld);
  };

  // LDS read offsets: off(row) = row*64 + ((lhi ^ ((row>>1)&3))<<4)
  int aoff[4], boff[2];
#pragma unroll
  for (int i = 0; i < 4; i++) {
    int r = wm * 64 + i * 16 + l15;
    aoff[i] = r * 64 + ((lhi ^ ((r >> 1) & 3)) << 4);
  }
#pragma unroll
  for (int j = 0; j < 2; j++) {
    int r = wn * 32 + j * 16 + l15;
    boff[j] = r * 64 + ((lhi ^ ((r >> 1) & 3)) << 4);
  }

  i32x4 acc[2][4][2] = {};   // [B-half][i][j]
  i32x4 afr[4], b0r[2], b1r[2];

  // prologue: A(0),B0(0),B1(0),A(1),B0(1); gate drains tile0
  stage(0, gA, 0); stage(1, gB0, 0); stage(2, gB1, 0);
  stage(0, gA, 1); stage(1, gB0, 1);
  asm volatile("s_waitcnt vmcnt(2)" ::: "memory");
  __builtin_amdgcn_sched_barrier(0);
  __builtin_amdgcn_s_barrier();
  __builtin_amdgcn_sched_barrier(0);

  for (int s = 0; s < NT; ++s) {
    const char* Ah  = &lds[s & 1][0][0];
    const char* B0h = &lds[s & 1][1][0];
    const char* B1h = &lds[s & 1][2][0];

    // ---- P0: read A(4)+B0(2); stage B1(s+1) [B1(s-1) slot: reads consumed P1(s-1)]
#pragma unroll
    for (int i = 0; i < 4; i++) afr[i] = *(const i32x4*)&Ah[aoff[i]];
#pragma unroll
    for (int j = 0; j < 2; j++) b0r[j] = *(const i32x4*)&B0h[boff[j]];
    stage(2, gB1, s + 1);
    PB();
    __builtin_amdgcn_s_setprio(1);
#pragma unroll
    for (int i = 0; i < 4; i++)
#pragma unroll
      for (int j = 0; j < 2; j++) ACCI(acc[0][i][j], afr[i], b0r[j]);
    __builtin_amdgcn_s_setprio(0);
    PB();

    // ---- P1: read B1(2); stage A,B0(s+2) [A(s)/B0(s) reads consumed P0]
#pragma unroll
    for (int j = 0; j < 2; j++) b1r[j] = *(const i32x4*)&B1h[boff[j]];
    stage(0, gA, s + 2);
    stage(1, gB0, s + 2);
    PB();
    __builtin_amdgcn_s_setprio(1);
#pragma unroll
    for (int i = 0; i < 4; i++)
#pragma unroll
      for (int j = 0; j < 2; j++) ACCI(acc[1][i][j], afr[i], b1r[j]);
    __builtin_amdgcn_s_setprio(0);
    // gate: drains tile s+1 {A,B0 @P1(s-1), B1 @P0(s)}; keeps {A,B0(s+2)}
    if (s >= NT - 2) { asm volatile("s_waitcnt vmcnt(0)" ::: "memory"); }
    else             { asm volatile("s_waitcnt vmcnt(2)" ::: "memory"); }
    __builtin_amdgcn_sched_barrier(0);
    __builtin_amdgcn_s_barrier();
    __builtin_amdgcn_sched_barrier(0);
  }

  // ---------------- epilogue (dequant) ----------------
#pragma unroll
  for (int i = 0; i < 4; i++) {
    int row = m0 + wm * 64 + i * 16 + lhi * 4;
    if (EPI == 0) {
      u16* out = (u16*)outp;
#pragma unroll
      for (int h = 0; h < 2; h++)
#pragma unroll
        for (int j = 0; j < 2; j++) {
          int colb = n0 + h * 128 + wn * 32 + j * 16;
          int col = colb + l15;
          int sh = colb >> 5;
          int d = (colb & 31) + l15;
          float bv = bias[col];
#pragma unroll
          for (int rg = 0; rg < 4; rg++)
            out[(size_t)sh * 2097152 + (size_t)(row + rg) * 32 + d] =
                f2bf((float)acc[h][i][j][rg] * INV_A + bv);
        }
    } else if (EPI == 1) {
      u16* sbw = (u16*)outp;
#pragma unroll
      for (int rg = 0; rg < 4; rg++) {
        int m = row + rg;
        int b = m >> 14, wi2 = (m >> 6) & 255, n = m & 63;
        int hh = (((wi2 >> 4) << 3) + (n >> 3) + 4) & 127;
        int w = (((wi2 & 15) << 3) + (n & 7) + 4) & 127;
        size_t pix = (((size_t)((b << 7) + hh) << 7) + (size_t)w) << 9;
#pragma unroll
        for (int h = 0; h < 2; h++)
#pragma unroll
          for (int j = 0; j < 2; j++) {
            int col = n0 + h * 128 + wn * 32 + j * 16 + l15;
            sbw[pix + col] = f2bf(resid[pix + col] +
                                  (float)acc[h][i][j][rg] * INV_P + bias[col]);
          }
      }
    } else if (EPI == 2) {
      float* out = (float*)outp;
      const u16* sbp = (const u16*)resid;
#pragma unroll
      for (int h = 0; h < 2; h++)
#pragma unroll
        for (int j = 0; j < 2; j++) {
          int col = n0 + h * 128 + wn * 32 + j * 16 + l15;
          float bv = bias[col];
#pragma unroll
          for (int rg = 0; rg < 4; rg++) {
            size_t idx = (size_t)(row + rg) * 512 + col;
            out[idx] = bf2f(sbp[idx]) + (float)acc[h][i][j][rg] * INV_H + bv;
          }
        }
    } else {
      char* out = (char*)outp;
#pragma unroll
      for (int j = 0; j < 2; j++) {
        int col = n0 + wn * 32 + j * 16 + l15;
        float ba_ = bias[col], bg_ = bias[col + 2048];
#pragma unroll
        for (int rg = 0; rg < 4; rg++) {
          float av = (float)acc[0][i][j][rg] * INV_A + ba_;
          float gv = (float)acc[1][i][j][rg] * INV_A + bg_;
          float sw = gv / (1.f + __expf(-gv));
          out[(size_t)(row + rg) * 2048 + col] = q8(sw * av, 64.f);
        }
      }
    }
  }
}

// ---------------- MFMA windowed attention (blocked bf16 qkv in, i8 out x32) -------
__global__ __launch_bounds__(256) void attn_mfma(
    const u16* __restrict__ qkv, char* __restrict__ out) {
  __shared__ __align__(16) char alds[4][15360];
  int tid = threadIdx.x;
  int wid = tid >> 6, lane = tid & 63;
  int bwin = blockIdx.x >> 2;
  int head = ((blockIdx.x & 3) << 2) + wid;
  int wi = bwin & 255;
  int wr = wi >> 4, wc = wi & 15;
  char* Wb = alds[wid];
  u16* Qr = (u16*)Wb;
  u16* Kr = (u16*)(Wb + 5120);
  u16* Vt = (u16*)(Wb + 10240);
  u16* PT = (u16*)Wb;
  int t = lane;
  int l15 = lane & 15, lhi = lane >> 4;
  size_t tok = (size_t)(bwin << 6) + t;
  const u16* qb = qkv + (size_t)head * 2097152 + tok * 32;
  union U { uint4 u; u16 s[8]; };
  U vq[4], vk[4], vv[4];
#pragma unroll
  for (int g = 0; g < 4; g++) {
    vq[g].u = *(const uint4*)(qb + (g << 3));
    vk[g].u = *(const uint4*)(qb + 33554432 + (g << 3));
    vv[g].u = *(const uint4*)(qb + 67108864 + (g << 3));
  }
  float q[32], k[32];
#pragma unroll
  for (int j = 0; j < 32; j++) {
    q[j] = bf2f(vq[j >> 3].s[j & 7]);
    k[j] = bf2f(vk[j >> 3].s[j & 7]);
  }
  int r = t >> 3, c = t & 7;
#pragma unroll
  for (int d = 0; d < 16; d++) {
    float pos = (d < 8) ? (float)r : (float)c;
    int dd = (d < 8) ? d : d - 8;
    float ang = pos * __expf(-(float)dd * 1.1512925465f);
    float sn, cs;
    __sincosf(ang, &sn, &cs);
    float q1 = q[d], q2 = q[d + 16];
    q[d] = q1 * cs - q2 * sn;  q[d + 16] = q2 * cs + q1 * sn;
    float k1 = k[d], k2 = k[d + 16];
    k[d] = k1 * cs - k2 * sn;  k[d + 16] = k2 * cs + k1 * sn;
  }
#pragma unroll
  for (int j = 0; j < 32; j++) q[j] *= 0.17677669529663687f;
#pragma unroll
  for (int sl = 0; sl < 4; sl++) {
    U tq, tk;
#pragma unroll
    for (int j = 0; j < 8; j++) { tq.s[j] = f2bf(q[sl * 8 + j]); tk.s[j] = f2bf(k[sl * 8 + j]); }
    *(uint4*)(Qr + t * 40 + sl * 8) = tq.u;
    *(uint4*)(Kr + t * 40 + sl * 8) = tk.u;
  }
#pragma unroll
  for (int j = 0; j < 32; j++) Vt[j * 72 + t] = vv[j >> 3].s[j & 7];
  bf16x8 kf[4], qf[4];
#pragma unroll
  for (int i = 0; i < 4; i++) {
    kf[i] = *(const bf16x8*)(Kr + (i * 16 + l15) * 40 + lhi * 8);
    qf[i] = *(const bf16x8*)(Qr + (i * 16 + l15) * 40 + lhi * 8);
  }
  f32x4 zz = {0.f, 0.f, 0.f, 0.f};
  f32x4 st[4][4];
#pragma unroll
  for (int mi = 0; mi < 4; mi++)
#pragma unroll
    for (int nj = 0; nj < 4; nj++)
      st[mi][nj] = __builtin_amdgcn_mfma_f32_16x16x32_bf16(kf[mi], qf[nj], zz, 0, 0, 0);
  if (wr == 15 || wc == 15) {
    int idh = (wr == 15) ? ((r >= 4) ? 2 : 1) : 0;
    int idw = (wc == 15) ? ((c >= 4) ? 2 : 1) : 0;
    int code = idh * 3 + idw;
    int cq[4], cm[4][4];
#pragma unroll
    for (int nj = 0; nj < 4; nj++) cq[nj] = __shfl(code, nj * 16 + l15);
#pragma unroll
    for (int mi = 0; mi < 4; mi++)
#pragma unroll
      for (int rg = 0; rg < 4; rg++) cm[mi][rg] = __shfl(code, mi * 16 + lhi * 4 + rg);
#pragma unroll
    for (int mi = 0; mi < 4; mi++)
#pragma unroll
      for (int nj = 0; nj < 4; nj++)
#pragma unroll
        for (int rg = 0; rg < 4; rg++)
          if (cm[mi][rg] != cq[nj]) st[mi][nj][rg] -= 100.f;
  }
  float inv_[4];
#pragma unroll
  for (int nj = 0; nj < 4; nj++) {
    float mx = -1e30f;
#pragma unroll
    for (int mi = 0; mi < 4; mi++)
#pragma unroll
      for (int rg = 0; rg < 4; rg++) mx = fmaxf(mx, st[mi][nj][rg]);
    mx = fmaxf(mx, __shfl_xor(mx, 16));
    mx = fmaxf(mx, __shfl_xor(mx, 32));
    float sum = 0.f;
#pragma unroll
    for (int mi = 0; mi < 4; mi++)
#pragma unroll
      for (int rg = 0; rg < 4; rg++) {
        float p = __expf(st[mi][nj][rg] - mx);
        st[mi][nj][rg] = p;
        sum += p;
      }
    sum += __shfl_xor(sum, 16);
    sum += __shfl_xor(sum, 32);
    inv_[nj] = 1.f / sum;
  }
#pragma unroll
  for (int mi = 0; mi < 4; mi++)
#pragma unroll
    for (int nj = 0; nj < 4; nj++) {
      uint32_t lo, hi;
      asm("v_cvt_pk_bf16_f32 %0, %1, %2" : "=v"(lo) : "v"(st[mi][nj][0]), "v"(st[mi][nj][1]));
      asm("v_cvt_pk_bf16_f32 %0, %1, %2" : "=v"(hi) : "v"(st[mi][nj][2]), "v"(st[mi][nj][3]));
      uint2 pr; pr.x = lo; pr.y = hi;
      *(uint2*)(PT + (nj * 16 + l15) * 72 + mi * 16 + lhi * 4) = pr;
    }
  bf16x8 vf[2][2], pf[4][2];
#pragma unroll
  for (int i = 0; i < 2; i++)
#pragma unroll
    for (int kc = 0; kc < 2; kc++)
      vf[i][kc] = *(const bf16x8*)(Vt + (i * 16 + l15) * 72 + kc * 32 + lhi * 8);
#pragma unroll
  for (int nj = 0; nj < 4; nj++)
#pragma unroll
    for (int kc = 0; kc < 2; kc++)
      pf[nj][kc] = *(const bf16x8*)(PT + (nj * 16 + l15) * 72 + kc * 32 + lhi * 8);
  char* Ot = Wb;
#pragma unroll
  for (int i = 0; i < 2; i++)
#pragma unroll
    for (int nj = 0; nj < 4; nj++) {
      f32x4 o = __builtin_amdgcn_mfma_f32_16x16x32_bf16(vf[i][0], pf[nj][0], zz, 0, 0, 0);
      o = __builtin_amdgcn_mfma_f32_16x16x32_bf16(vf[i][1], pf[nj][1], o, 0, 0, 0);
      float iv32 = inv_[nj] * 32.f;
      uint32_t pk = q8x4(o[0] * iv32, o[1] * iv32, o[2] * iv32, o[3] * iv32, 1.f);
      *(uint32_t*)(Ot + (nj * 16 + l15) * 40 + i * 16 + lhi * 4) = pk;
    }
#pragma unroll
  for (int g = 0; g < 4; g++) {
    int tl = g * 16 + (lane >> 2);
    int ch_ = (lane & 3) << 3;
    uint2 v = *(const uint2*)(Ot + tl * 40 + ch_);
    *(uint2*)(out + (size_t)((bwin << 6) + tl) * 512 + (head << 5) + ch_) = v;
  }
}

// ---------------- launch ----------------
extern "C" void kernel_launch(void* const* d_in, const int* in_sizes, int n_in,
                              void* d_out, int out_size, void* d_ws, size_t ws_size,
                              hipStream_t stream) {
  (void)in_sizes; (void)n_in; (void)out_size; (void)ws_size;
  const float* x      = (const float*)d_in[0];
  const float* n1g    = (const float*)d_in[2];
  const float* n1b    = (const float*)d_in[3];
  const float* qkv_w  = (const float*)d_in[4];
  const float* qkv_b  = (const float*)d_in[5];
  const float* proj_w = (const float*)d_in[6];
  const float* proj_b = (const float*)d_in[7];
  const float* n2g    = (const float*)d_in[8];
  const float* n2b    = (const float*)d_in[9];
  const float* fc1_w  = (const float*)d_in[10];
  const float* fc1_b  = (const float*)d_in[11];
  const float* fc2_w  = (const float*)d_in[12];
  const float* fc2_b  = (const float*)d_in[13];

  const size_t MB = 1048576ULL;
  char* ws = (char*)d_ws;
  char* wb8  = ws;                        // [0,4MB): qkv|proj|fc1|fc2 i8 weights
  char* wq8  = wb8;
  char* wp8  = wb8 + 786432;
  char* wf18 = wb8 + 1048576;
  char* wf28 = wb8 + 3145728;
  char* xw8  = ws + 8 * MB;               // [8,40): LN1 i8; later attn8
  char* attn8 = xw8;
  u16*  qkvb = (u16*)(ws + 72 * MB);      // [72,264): blocked bf16 qkv
  char* hb8  = ws + 8 * MB;               // [8,136): fc1 i8 h (qkv/attn dead)
  u16*  sb   = (u16*)(ws + 264 * MB);     // [264,328): bf16 residual s
  char* yb8  = ws + 328 * MB;             // [328,360): LN2 i8 out

  ln1_wconv<<<20480, 256, 0, stream>>>(x, n1g, n1b, xw8,
                                       qkv_w, proj_w, fc1_w, fc2_w, wb8);
  gemm2i<0, 512><<<3072, 512, 0, stream>>>(xw8, wq8, qkv_b, qkvb, nullptr, 6);
  attn_mfma<<<4096, 256, 0, stream>>>(qkvb, attn8);
  gemm2i<1, 512><<<1024, 512, 0, stream>>>(attn8, wp8, proj_b, sb, x, 2);
  ln2_q8<<<16384, 256, 0, stream>>>(sb, n2g, n2b, yb8);
  gemm2i<3, 512><<<8192, 512, 0, stream>>>(yb8, wf18, fc1_b, hb8, nullptr, 16);
  gemm2i<2, 2048><<<1024, 512, 0, stream>>>(hb8, wf28, fc2_b, d_out,
                                            (const float*)sb, 2);
}